// Round 10
// baseline (171.073 us; speedup 1.0000x reference)
//
#include <hip/hip_runtime.h>
#include <hip/hip_bf16.h>
#include <hip/hip_fp16.h>

#define HW 4096

typedef _Float16 f16x8 __attribute__((ext_vector_type(8)));
typedef float f32x4 __attribute__((ext_vector_type(4)));

#define FOR8(X) X(0) X(1) X(2) X(3) X(4) X(5) X(6) X(7)

static __device__ __forceinline__ __half2 u2h(unsigned int u) {
    union { unsigned int u; __half2 h; } c; c.u = u; return c.h;
}
static __device__ __forceinline__ unsigned int h2u(__half2 h) {
    union { unsigned int u; __half2 h; } c; c.h = h; return c.u;
}
static __device__ __forceinline__ f16x8 uint4_as_f16x8(uint4 v) {
    union { uint4 u; f16x8 f; } c; c.u = v; return c.f;
}

// ---------------- K0b: w3 -> fp16 MFMA A-fragment order (HW-verified R4) ----------------
__global__ __launch_bounds__(256) void k0b_w3h(const float* __restrict__ w3, ushort* __restrict__ w3h) {
    int gi = blockIdx.x * 256 + threadIdx.x;       // 64*64*8 = 32768
    if (gi >= 32768) return;
    int j = gi & 7;
    int l = (gi >> 3) & 63;
    int p = gi >> 9;                                // ic*8+oc
    int ic = p >> 3, oc = p & 7;
    int od = l & 15;
    int m  = ((l >> 4) << 3) + j;
    __half h = __float2half(w3[(size_t)((ic * 128 + oc * 16 + od) * 32 + m)]);
    w3h[gi] = __half_as_ushort(h);
}

// ---------------- K0c: w2 -> fp16 MFMA A-fragment order ----------------
__global__ __launch_bounds__(256) void k0c_w2f(const float* __restrict__ w2, ushort* __restrict__ w2f) {
    int gi = blockIdx.x * 256 + threadIdx.x;       // 8*9*2*64*8 = 73728
    if (gi >= 73728) return;
    int j   = gi & 7;
    int l   = (gi >> 3) & 63;
    int h   = (gi >> 9) & 1;
    int tap = (gi >> 10) % 9;
    int g   = gi / 9216;
    int co = h * 16 + (l & 15);
    int ci = ((l >> 4) << 3) + j;
    float v = w2[(size_t)((g * 32 + co) * 32 + ci) * 9 + tap];
    w2f[gi] = __half_as_ushort(__float2half(v));
}

// ---------------- K1: relu(x) -> 1x1 conv -> relu -> h1g fp16 [b][g][px][32] ----------------
__global__ __launch_bounds__(256) void k1_conv1(const float* __restrict__ x, const float* __restrict__ w1,
                                                const float* __restrict__ b1, ushort* __restrict__ h1g) {
    int bi = blockIdx.x;                 // ((b*8 + g)*16 + chunk)
    int chunk = bi & 15;
    int g = (bi >> 4) & 7;
    int b = bi >> 7;
    int pos = chunk * 256 + threadIdx.x;

    const float* xb = x + (size_t)(b * 128 + g * 16) * HW + pos;
    float xv[16];
#pragma unroll
    for (int i = 0; i < 16; ++i) xv[i] = fmaxf(xb[i * HW], 0.f);

    const float* wg = w1 + g * 32 * 16;
    const float* bg = b1 + g * 32;
    ushort hv[32];
#pragma unroll
    for (int m = 0; m < 32; ++m) {
        float acc = bg[m];
#pragma unroll
        for (int i = 0; i < 16; ++i) acc = fmaf(xv[i], wg[m * 16 + i], acc);
        hv[m] = __half_as_ushort(__float2half(fmaxf(acc, 0.f)));
    }
    ushort* hb = h1g + ((size_t)(b * 8 + g) * HW + pos) * 32;
#pragma unroll
    for (int q = 0; q < 4; ++q) *(uint4*)&hb[q * 8] = *(uint4*)&hv[q * 8];
}

// ---------------- K2: grouped 3x3 SAME conv via MFMA (9 shifted 1x1 GEMMs), no LDS ----------------
__global__ __launch_bounds__(256) void k2_conv2(const ushort* __restrict__ h1g, const ushort* __restrict__ w2f,
                                                const float* __restrict__ b2, ushort* __restrict__ h2g) {
    int bi = blockIdx.x;                 // b*512 + g*64 + pt
    int pt = bi & 63;
    int g  = (bi >> 6) & 7;
    int b  = bi >> 9;
    int t  = threadIdx.x;
    int w  = t >> 6, l = t & 63;
    int pxbase = pt * 64 + w * 16;
    int kgrp = l >> 4;

    int y = pxbase >> 6;
    int x = (pxbase & 63) + (l & 15);

    const ushort* hbase = h1g + (size_t)(b * 8 + g) * HW * 32;
    f16x8 Bf[9];
#pragma unroll
    for (int dy = -1; dy <= 1; ++dy) {
        int yy = y + dy;
        int yyc = yy < 0 ? 0 : (yy > 63 ? 63 : yy);
        bool rv = (yy >= 0) && (yy < 64);
#pragma unroll
        for (int dx = -1; dx <= 1; ++dx) {
            int xx = x + dx;
            int xc = xx < 0 ? 0 : (xx > 63 ? 63 : xx);
            uint4 v = *(const uint4*)&hbase[((yyc << 6) + xc) * 32 + kgrp * 8];
            bool ok = rv && (xx >= 0) && (xx < 64);
            v.x = ok ? v.x : 0u; v.y = ok ? v.y : 0u;
            v.z = ok ? v.z : 0u; v.w = ok ? v.w : 0u;
            Bf[(dy + 1) * 3 + (dx + 1)] = uint4_as_f16x8(v);
        }
    }

    const ushort* wg = w2f + (size_t)g * 9216;     // [tap][h][64][8]
    f16x8 Af[9][2];
#pragma unroll
    for (int tap = 0; tap < 9; ++tap)
#pragma unroll
        for (int h = 0; h < 2; ++h)
            Af[tap][h] = *(const f16x8*)&wg[((tap * 2 + h) * 64 + l) * 8];

    f32x4 acc[2];
#pragma unroll
    for (int h = 0; h < 2; ++h) {
        float4 bias = *(const float4*)(b2 + g * 32 + h * 16 + kgrp * 4);
        acc[h][0] = bias.x; acc[h][1] = bias.y; acc[h][2] = bias.z; acc[h][3] = bias.w;
    }
#pragma unroll
    for (int tap = 0; tap < 9; ++tap) {
#pragma unroll
        for (int h = 0; h < 2; ++h)
            acc[h] = __builtin_amdgcn_mfma_f32_16x16x32_f16(Af[tap][h], Bf[tap], acc[h], 0, 0, 0);
    }

    int px = pxbase + (l & 15);
    ushort* ob = h2g + ((size_t)(b * 8 + g) * HW + px) * 32;
#pragma unroll
    for (int h = 0; h < 2; ++h) {
        __half2 lo = __floats2half2_rn(fmaxf(acc[h][0], 0.f), fmaxf(acc[h][1], 0.f));
        __half2 hi = __floats2half2_rn(fmaxf(acc[h][2], 0.f), fmaxf(acc[h][3], 0.f));
        uint2 wv; wv.x = h2u(lo); wv.y = h2u(hi);
        *(uint2*)&ob[h * 16 + kgrp * 4] = wv;
    }
}

// ---------------- K3a: conv3 via MFMA -> ug fp16 [b_rel][px][oc*128+ic*16+od] ----------------
// Chunked over batches: processes NB_CHUNK=2 batches starting at base_b; ug holds only
// this chunk (16 MB, overlays dead h1g). 512 thr = 8 waves, wave = ic; pure streaming.
__global__ __launch_bounds__(512) void k3a_conv3(const ushort* __restrict__ h2g, const ushort* __restrict__ w3h,
                                                 const float* __restrict__ b3, ushort* __restrict__ ug,
                                                 int base_b) {
    int bid  = blockIdx.x;               // brel*256 + px-tile
    int brel = bid >> 8;
    int b    = base_b + brel;
    int px0  = (bid & 255) << 4;
    int t    = threadIdx.x;
    int ic   = t >> 6, l = t & 63;
    int lk   = l >> 4;
    int px   = px0 + (l & 15);

    f16x8 bf = *(const f16x8*)&h2g[(((size_t)(b * 8 + ic)) * HW + px) * 32 + lk * 8];
    ushort* ub = ug + ((size_t)(brel * 4096 + px)) * 1024 + ic * 16 + lk * 4;

#pragma unroll
    for (int oc = 0; oc < 8; ++oc) {
        f16x8 af = *(const f16x8*)&w3h[((ic * 8 + oc) * 64 + l) * 8];
        float4 bv = *(const float4*)(b3 + ic * 128 + oc * 16 + lk * 4);
        f32x4 c0; c0[0] = bv.x; c0[1] = bv.y; c0[2] = bv.z; c0[3] = bv.w;
        f32x4 d = __builtin_amdgcn_mfma_f32_16x16x32_f16(af, bf, c0, 0, 0, 0);
        __half2 lo = __floats2half2_rn(d[0], d[1]);
        __half2 hi = __floats2half2_rn(d[2], d[3]);
        uint2 wv; wv.x = h2u(lo); wv.y = h2u(hi);
        *(uint2*)&ub[oc * 128] = wv;
    }
}

// ---------------- K3b: routing only; od split across lane pairs; no atomics ----------------
// Block = (bo_rel, 128-px chunk); thread = (px_l = t>>1, odh = t&1).
// State: 8 named uint4 (u fp16) = 32 VGPR; cvt on use. s -> sbuf[bo][px][16od].
__global__ __launch_bounds__(256) void k3b_route(const ushort* __restrict__ ug, float* __restrict__ sOut,
                                                 float* __restrict__ part, int base_b) {
    __shared__ float sm[256][9];     // pad 9: conflict-free stride
    int bid   = blockIdx.x;          // bo_rel*32 + chunk
    int chunk = bid & 31;
    int bo_rel = bid >> 5;
    int b_rel = bo_rel >> 3, oc = bo_rel & 7;
    int b     = base_b + b_rel;
    int bo    = b * 8 + oc;
    int t     = threadIdx.x;
    int odh   = t & 1, pxl = t >> 1;
    int px    = chunk * 128 + pxl;

    const ushort* ub = ug + ((size_t)(b_rel * 4096 + px)) * 1024 + oc * 128 + odh * 8;
#define LDQ(i) uint4 q##i = *(const uint4*)&ub[(i) * 16];
    FOR8(LDQ)
#undef LDQ

#define UNP(i) float2 f0 = __half22float2(u2h(q##i.x)), f1 = __half22float2(u2h(q##i.y)), \
                      f2 = __half22float2(u2h(q##i.z)), f3 = __half22float2(u2h(q##i.w));

    // squash scale per ic
#define SC(i) float sc##i; { UNP(i) \
        float sp = f0.x*f0.x + f0.y*f0.y + f1.x*f1.x + f1.y*f1.y \
                 + f2.x*f2.x + f2.y*f2.y + f3.x*f3.x + f3.y*f3.y; \
        sp += __shfl_xor(sp, 1); \
        sc##i = sp / ((0.5f + sp) * (sqrtf(sp + 1e-6f) + 1e-6f)); }
    FOR8(SC)
#undef SC

#define BRI(i) float br##i = 0.f;
    FOR8(BRI)
#undef BRI

    float s0, s1, s2, s3, s4, s5, s6, s7;
#pragma unroll
    for (int it = 0; it < 2; ++it) {
#define CSC(i) float cs##i = sc##i / (1.f + __expf(-br##i));
        FOR8(CSC)
#undef CSC
        s0 = s1 = s2 = s3 = s4 = s5 = s6 = s7 = 0.f;
#define SVA(i) { UNP(i) \
        s0 = fmaf(f0.x, cs##i, s0); s1 = fmaf(f0.y, cs##i, s1); \
        s2 = fmaf(f1.x, cs##i, s2); s3 = fmaf(f1.y, cs##i, s3); \
        s4 = fmaf(f2.x, cs##i, s4); s5 = fmaf(f2.y, cs##i, s5); \
        s6 = fmaf(f3.x, cs##i, s6); s7 = fmaf(f3.y, cs##i, s7); }
        FOR8(SVA)
#undef SVA
        float sp = s0*s0 + s1*s1 + s2*s2 + s3*s3 + s4*s4 + s5*s5 + s6*s6 + s7*s7;
        sp += __shfl_xor(sp, 1);
        float f = sp / ((0.5f + sp) * (sqrtf(sp + 1e-6f) + 1e-6f));
#define DOTD(i) { UNP(i) \
        float dp = f0.x*s0 + f0.y*s1 + f1.x*s2 + f1.y*s3 + f2.x*s4 + f2.y*s5 + f3.x*s6 + f3.y*s7; \
        dp += __shfl_xor(dp, 1); \
        br##i = fmaf(sc##i * f, dp, br##i); }
        FOR8(DOTD)
#undef DOTD
    }

#define CF(i) float cf##i = 1.f / (1.f + __expf(-br##i));
    FOR8(CF)
#undef CF
    s0 = s1 = s2 = s3 = s4 = s5 = s6 = s7 = 0.f;
#define FS(i) { UNP(i) \
        s0 = fmaf(f0.x, cf##i, s0); s1 = fmaf(f0.y, cf##i, s1); \
        s2 = fmaf(f1.x, cf##i, s2); s3 = fmaf(f1.y, cf##i, s3); \
        s4 = fmaf(f2.x, cf##i, s4); s5 = fmaf(f2.y, cf##i, s5); \
        s6 = fmaf(f3.x, cf##i, s6); s7 = fmaf(f3.y, cf##i, s7); }
    FOR8(FS)
#undef FS
#undef UNP

    // store s: [bo][px][16], own half at odh*8 (fully coalesced 32B/lane)
    float* sb = sOut + ((size_t)bo * 4096 + px) * 16 + odh * 8;
    float4 va; va.x = s0; va.y = s1; va.z = s2; va.w = s3;
    float4 vb; vb.x = s4; vb.y = s5; vb.z = s6; vb.w = s7;
    *(float4*)&sb[0] = va;
    *(float4*)&sb[4] = vb;

    // block-level mean partial over 128 px
    sm[t][0] = s0; sm[t][1] = s1; sm[t][2] = s2; sm[t][3] = s3;
    sm[t][4] = s4; sm[t][5] = s5; sm[t][6] = s6; sm[t][7] = s7;
    __syncthreads();
    if (t < 16) {
        int oh = t >> 3, j = t & 7;
        float a = 0.f;
        for (int p = 0; p < 128; ++p) a += sm[p * 2 + oh][j];
        part[(size_t)(bo * 32 + chunk) * 16 + oh * 8 + j] = a;
    }
}

// ---------------- K4: reduce partials -> mean_hw; avg + stats ----------------
__global__ __launch_bounds__(256) void k4_avg(const float* __restrict__ sIn, const float* __restrict__ part,
                                              float* __restrict__ avg, float* __restrict__ stats) {
    __shared__ float mh[16];
    int bi = blockIdx.x;                 // bo*16 + chunk
    int chunk = bi & 15;
    int bo = bi >> 4;
    int t = threadIdx.x;
    int pos = chunk * 256 + t;

    if (t < 16) {
        float a = 0.f;
        for (int c = 0; c < 32; ++c) a += part[(size_t)(bo * 32 + c) * 16 + t];
        mh[t] = a * (1.f / 4096.f);
    }
    __syncthreads();

    const float* sb = sIn + ((size_t)bo * 4096 + pos) * 16;
    float4 r0 = *(const float4*)&sb[0];
    float4 r1 = *(const float4*)&sb[4];
    float4 r2 = *(const float4*)&sb[8];
    float4 r3 = *(const float4*)&sb[12];
    float a = r0.x * mh[0] + r0.y * mh[1] + r0.z * mh[2] + r0.w * mh[3]
            + r1.x * mh[4] + r1.y * mh[5] + r1.z * mh[6] + r1.w * mh[7]
            + r2.x * mh[8] + r2.y * mh[9] + r2.z * mh[10] + r2.w * mh[11]
            + r3.x * mh[12] + r3.y * mh[13] + r3.z * mh[14] + r3.w * mh[15];
    avg[(size_t)bo * 4096 + pos] = a;

    float p1 = a, p2 = a * a;
#pragma unroll
    for (int m = 1; m < 64; m <<= 1) {
        p1 += __shfl_xor(p1, m);
        p2 += __shfl_xor(p2, m);
    }
    if ((t & 63) == 0) {
        atomicAdd(&stats[bo * 2],     p1);
        atomicAdd(&stats[bo * 2 + 1], p2);
    }
}

// ---------------- K5: normalize, attn gate, residual ----------------
__global__ __launch_bounds__(256) void k5_out(const float* __restrict__ sIn, const float* __restrict__ x,
                                              const float* __restrict__ avg, const float* __restrict__ stats,
                                              const float* __restrict__ aw, const float* __restrict__ ab,
                                              float* __restrict__ out) {
    int bi = blockIdx.x;                 // bo*16 + chunk
    int chunk = bi & 15;
    int bo = bi >> 4;
    int oc = bo & 7;
    int pos = chunk * 256 + threadIdx.x;

    float sum = stats[bo * 2], sumsq = stats[bo * 2 + 1];
    float m   = sum * (1.f / 4096.f);
    float var = (sumsq - 4096.f * m * m) * (1.f / 4095.f);
    float sd  = sqrtf(fmaxf(var, 0.f)) + 1e-6f;

    float t   = (avg[(size_t)bo * 4096 + pos] - m) / sd * aw[oc] + ab[oc];
    float sig = 1.f / (1.f + __expf(-t));

    const float* sb = sIn + ((size_t)bo * 4096 + pos) * 16;
    float4 r0 = *(const float4*)&sb[0];
    float4 r1 = *(const float4*)&sb[4];
    float4 r2 = *(const float4*)&sb[8];
    float4 r3 = *(const float4*)&sb[12];
    float sv[16] = {r0.x, r0.y, r0.z, r0.w, r1.x, r1.y, r1.z, r1.w,
                    r2.x, r2.y, r2.z, r2.w, r3.x, r3.y, r3.z, r3.w};

    const float* xb = x + (size_t)bo * 16 * HW + pos;
    float* ob = out + (size_t)bo * 16 * HW + pos;
#pragma unroll
    for (int od = 0; od < 16; ++od) ob[od * HW] = fmaf(sv[od], sig, xb[od * HW]);
}

extern "C" void kernel_launch(void* const* d_in, const int* in_sizes, int n_in,
                              void* d_out, int out_size, void* d_ws, size_t ws_size,
                              hipStream_t stream) {
    const float* x  = (const float*)d_in[0];
    const float* w1 = (const float*)d_in[1];
    const float* b1 = (const float*)d_in[2];
    const float* w2 = (const float*)d_in[3];
    const float* b2 = (const float*)d_in[4];
    const float* w3 = (const float*)d_in[5];
    const float* b3 = (const float*)d_in[6];
    const float* aw = (const float*)d_in[7];
    const float* ab = (const float*)d_in[8];

    float* ws      = (float*)d_ws;
    ushort* h1g    = (ushort*)ws;                    // 8.4M halfs (16MB); dead after k2
    ushort* ug     = h1g;                            // per-chunk u: 2*4096*1024 halfs = 16MB exactly
    ushort* h2g    = (ushort*)(ws + 4194304);        // 8.4M halfs (16MB)
    float* sbuf    = ws + 8388608;                   // 4,194,304 floats [64][4096][16]
    float* avg     = sbuf + 4194304;                 // 262,144
    float* part    = avg + 262144;                   // 32,768
    float* stats   = part + 32768;                   // 128
    ushort* w3h    = (ushort*)(stats + 128);         // 32,768 halfs
    ushort* w2f    = w3h + 32768;                    // 73,728 halfs
    // total ~51.7 MB (same as R8, proven safe)

    hipMemsetAsync(stats, 0, 128 * sizeof(float), stream);
    k0b_w3h <<<128, 256, 0, stream>>>(w3, w3h);
    k0c_w2f <<<288, 256, 0, stream>>>(w2, w2f);
    k1_conv1<<<1024, 256, 0, stream>>>(x, w1, b1, h1g);
    k2_conv2<<<4096, 256, 0, stream>>>(h1g, w2f, b2, h2g);
    for (int base_b = 0; base_b < 8; base_b += 2) {
        k3a_conv3<<<512, 512, 0, stream>>>(h2g, w3h, b3, ug, base_b);
        k3b_route<<<512, 256, 0, stream>>>(ug, sbuf, part, base_b);
    }
    k4_avg  <<<1024, 256, 0, stream>>>(sbuf, part, avg, stats);
    k5_out  <<<1024, 256, 0, stream>>>(sbuf, x, avg, stats, aw, ab, (float*)d_out);
}

// Round 11
// 118.264 us; speedup vs baseline: 1.4465x; 1.4465x over previous
//
#include <hip/hip_runtime.h>
#include <hip/hip_bf16.h>
#include <hip/hip_fp16.h>

#define HW 4096

typedef _Float16 f16x8 __attribute__((ext_vector_type(8)));
typedef float f32x4 __attribute__((ext_vector_type(4)));

#define FOR8(X) X(0) X(1) X(2) X(3) X(4) X(5) X(6) X(7)

static __device__ __forceinline__ __half2 u2h(unsigned int u) {
    union { unsigned int u; __half2 h; } c; c.u = u; return c.h;
}
static __device__ __forceinline__ unsigned int h2u(__half2 h) {
    union { unsigned int u; __half2 h; } c; c.h = h; return c.u;
}
static __device__ __forceinline__ f16x8 uint4_as_f16x8(uint4 v) {
    union { uint4 u; f16x8 f; } c; c.u = v; return c.f;
}

// ---------------- K0b: w3 -> fp16 MFMA A-fragment order (HW-verified R4) ----------------
__global__ __launch_bounds__(256) void k0b_w3h(const float* __restrict__ w3, ushort* __restrict__ w3h) {
    int gi = blockIdx.x * 256 + threadIdx.x;       // 64*64*8 = 32768
    if (gi >= 32768) return;
    int j = gi & 7;
    int l = (gi >> 3) & 63;
    int p = gi >> 9;                                // ic*8+oc
    int ic = p >> 3, oc = p & 7;
    int od = l & 15;
    int m  = ((l >> 4) << 3) + j;
    __half h = __float2half(w3[(size_t)((ic * 128 + oc * 16 + od) * 32 + m)]);
    w3h[gi] = __half_as_ushort(h);
}

// ---------------- K0c: w2 -> fp16 MFMA A-fragment order ----------------
__global__ __launch_bounds__(256) void k0c_w2f(const float* __restrict__ w2, ushort* __restrict__ w2f) {
    int gi = blockIdx.x * 256 + threadIdx.x;       // 8*9*2*64*8 = 73728
    if (gi >= 73728) return;
    int j   = gi & 7;
    int l   = (gi >> 3) & 63;
    int h   = (gi >> 9) & 1;
    int tap = (gi >> 10) % 9;
    int g   = gi / 9216;
    int co = h * 16 + (l & 15);
    int ci = ((l >> 4) << 3) + j;
    float v = w2[(size_t)((g * 32 + co) * 32 + ci) * 9 + tap];
    w2f[gi] = __half_as_ushort(__float2half(v));
}

// ---------------- K1: relu(x) -> 1x1 conv -> relu -> h1g fp16 [b][g][px][32] ----------------
__global__ __launch_bounds__(256) void k1_conv1(const float* __restrict__ x, const float* __restrict__ w1,
                                                const float* __restrict__ b1, ushort* __restrict__ h1g) {
    int bi = blockIdx.x;                 // ((b*8 + g)*16 + chunk)
    int chunk = bi & 15;
    int g = (bi >> 4) & 7;
    int b = bi >> 7;
    int pos = chunk * 256 + threadIdx.x;

    const float* xb = x + (size_t)(b * 128 + g * 16) * HW + pos;
    float xv[16];
#pragma unroll
    for (int i = 0; i < 16; ++i) xv[i] = fmaxf(xb[i * HW], 0.f);

    const float* wg = w1 + g * 32 * 16;
    const float* bg = b1 + g * 32;
    ushort hv[32];
#pragma unroll
    for (int m = 0; m < 32; ++m) {
        float acc = bg[m];
#pragma unroll
        for (int i = 0; i < 16; ++i) acc = fmaf(xv[i], wg[m * 16 + i], acc);
        hv[m] = __half_as_ushort(__float2half(fmaxf(acc, 0.f)));
    }
    ushort* hb = h1g + ((size_t)(b * 8 + g) * HW + pos) * 32;
#pragma unroll
    for (int q = 0; q < 4; ++q) *(uint4*)&hb[q * 8] = *(uint4*)&hv[q * 8];
}

// ---------------- K2: grouped 3x3 SAME conv via MFMA (9 shifted 1x1 GEMMs), no LDS ----------------
__global__ __launch_bounds__(256) void k2_conv2(const ushort* __restrict__ h1g, const ushort* __restrict__ w2f,
                                                const float* __restrict__ b2, ushort* __restrict__ h2g) {
    int bi = blockIdx.x;                 // b*512 + g*64 + pt
    int pt = bi & 63;
    int g  = (bi >> 6) & 7;
    int b  = bi >> 9;
    int t  = threadIdx.x;
    int w  = t >> 6, l = t & 63;
    int pxbase = pt * 64 + w * 16;
    int kgrp = l >> 4;

    int y = pxbase >> 6;
    int x = (pxbase & 63) + (l & 15);

    const ushort* hbase = h1g + (size_t)(b * 8 + g) * HW * 32;
    f16x8 Bf[9];
#pragma unroll
    for (int dy = -1; dy <= 1; ++dy) {
        int yy = y + dy;
        int yyc = yy < 0 ? 0 : (yy > 63 ? 63 : yy);
        bool rv = (yy >= 0) && (yy < 64);
#pragma unroll
        for (int dx = -1; dx <= 1; ++dx) {
            int xx = x + dx;
            int xc = xx < 0 ? 0 : (xx > 63 ? 63 : xx);
            uint4 v = *(const uint4*)&hbase[((yyc << 6) + xc) * 32 + kgrp * 8];
            bool ok = rv && (xx >= 0) && (xx < 64);
            v.x = ok ? v.x : 0u; v.y = ok ? v.y : 0u;
            v.z = ok ? v.z : 0u; v.w = ok ? v.w : 0u;
            Bf[(dy + 1) * 3 + (dx + 1)] = uint4_as_f16x8(v);
        }
    }

    const ushort* wg = w2f + (size_t)g * 9216;     // [tap][h][64][8]
    f16x8 Af[9][2];
#pragma unroll
    for (int tap = 0; tap < 9; ++tap)
#pragma unroll
        for (int h = 0; h < 2; ++h)
            Af[tap][h] = *(const f16x8*)&wg[((tap * 2 + h) * 64 + l) * 8];

    f32x4 acc[2];
#pragma unroll
    for (int h = 0; h < 2; ++h) {
        float4 bias = *(const float4*)(b2 + g * 32 + h * 16 + kgrp * 4);
        acc[h][0] = bias.x; acc[h][1] = bias.y; acc[h][2] = bias.z; acc[h][3] = bias.w;
    }
#pragma unroll
    for (int tap = 0; tap < 9; ++tap) {
#pragma unroll
        for (int h = 0; h < 2; ++h)
            acc[h] = __builtin_amdgcn_mfma_f32_16x16x32_f16(Af[tap][h], Bf[tap], acc[h], 0, 0, 0);
    }

    int px = pxbase + (l & 15);
    ushort* ob = h2g + ((size_t)(b * 8 + g) * HW + px) * 32;
#pragma unroll
    for (int h = 0; h < 2; ++h) {
        __half2 lo = __floats2half2_rn(fmaxf(acc[h][0], 0.f), fmaxf(acc[h][1], 0.f));
        __half2 hi = __floats2half2_rn(fmaxf(acc[h][2], 0.f), fmaxf(acc[h][3], 0.f));
        uint2 wv; wv.x = h2u(lo); wv.y = h2u(hi);
        *(uint2*)&ob[h * 16 + kgrp * 4] = wv;
    }
}

// ---------------- K3a: conv3 MFMA -> LDS staging -> coalesced ug fp16 [b_rel*4096+px][1024] ----------------
// ch layout inside row: oc*128 + ic*16 + od (matches k3b). 512 thr = 8 waves (wave=ic), 16 px/block.
// LDS [16][1032] padded (2-way write, 4-way read conflicts only). Writeout: 512B-contiguous runs.
__global__ __launch_bounds__(512) void k3a_conv3(const ushort* __restrict__ h2g, const ushort* __restrict__ w3h,
                                                 const float* __restrict__ b3, ushort* __restrict__ ug,
                                                 int base_b) {
    __shared__ ushort us[16][1032];
    int bid  = blockIdx.x;               // brel*256 + px-tile
    int brel = bid >> 8;
    int b    = base_b + brel;
    int px0  = (bid & 255) << 4;
    int t    = threadIdx.x;
    int ic   = t >> 6, l = t & 63;
    int lk   = l >> 4, lrow = l & 15;
    int px   = px0 + lrow;

    f16x8 bf = *(const f16x8*)&h2g[(((size_t)(b * 8 + ic)) * HW + px) * 32 + lk * 8];

#pragma unroll
    for (int oc = 0; oc < 8; ++oc) {
        f16x8 af = *(const f16x8*)&w3h[((ic * 8 + oc) * 64 + l) * 8];
        float4 bv = *(const float4*)(b3 + ic * 128 + oc * 16 + lk * 4);
        f32x4 c0; c0[0] = bv.x; c0[1] = bv.y; c0[2] = bv.z; c0[3] = bv.w;
        f32x4 d = __builtin_amdgcn_mfma_f32_16x16x32_f16(af, bf, c0, 0, 0, 0);
        __half2 lo = __floats2half2_rn(d[0], d[1]);
        __half2 hi = __floats2half2_rn(d[2], d[3]);
        uint2 wv; wv.x = h2u(lo); wv.y = h2u(hi);
        *(uint2*)&us[lrow][oc * 128 + ic * 16 + lk * 4] = wv;
    }
    __syncthreads();

    // writeout: thread = (pxw = t>>5, li = t&31); q loop covers 1024 ch
    int pxw = t >> 5, li = t & 31;
    ushort* ub = ug + ((size_t)(brel * 4096 + px0 + pxw)) * 1024;
#pragma unroll
    for (int q = 0; q < 4; ++q) {
        int ch = q * 256 + li * 8;
        *(uint4*)&ub[ch] = *(const uint4*)&us[pxw][ch];
    }
}

// ---------------- K3b: routing only; od split across lane pairs; sbuf fp16 ----------------
__global__ __launch_bounds__(256) void k3b_route(const ushort* __restrict__ ug, ushort* __restrict__ sOut,
                                                 float* __restrict__ part, int base_b) {
    __shared__ float sm[256][9];
    int bid    = blockIdx.x;          // bo_rel*32 + chunk
    int chunk  = bid & 31;
    int bo_rel = bid >> 5;
    int b_rel  = bo_rel >> 3, oc = bo_rel & 7;
    int b      = base_b + b_rel;
    int bo     = b * 8 + oc;
    int t      = threadIdx.x;
    int odh    = t & 1, pxl = t >> 1;
    int px     = chunk * 128 + pxl;

    const ushort* ub = ug + ((size_t)(b_rel * 4096 + px)) * 1024 + oc * 128 + odh * 8;
#define LDQ(i) uint4 q##i = *(const uint4*)&ub[(i) * 16];
    FOR8(LDQ)
#undef LDQ

#define UNP(i) float2 f0 = __half22float2(u2h(q##i.x)), f1 = __half22float2(u2h(q##i.y)), \
                      f2 = __half22float2(u2h(q##i.z)), f3 = __half22float2(u2h(q##i.w));

#define SC(i) float sc##i; { UNP(i) \
        float sp = f0.x*f0.x + f0.y*f0.y + f1.x*f1.x + f1.y*f1.y \
                 + f2.x*f2.x + f2.y*f2.y + f3.x*f3.x + f3.y*f3.y; \
        sp += __shfl_xor(sp, 1); \
        sc##i = sp / ((0.5f + sp) * (sqrtf(sp + 1e-6f) + 1e-6f)); }
    FOR8(SC)
#undef SC

#define BRI(i) float br##i = 0.f;
    FOR8(BRI)
#undef BRI

    float s0, s1, s2, s3, s4, s5, s6, s7;
#pragma unroll
    for (int it = 0; it < 2; ++it) {
#define CSC(i) float cs##i = sc##i / (1.f + __expf(-br##i));
        FOR8(CSC)
#undef CSC
        s0 = s1 = s2 = s3 = s4 = s5 = s6 = s7 = 0.f;
#define SVA(i) { UNP(i) \
        s0 = fmaf(f0.x, cs##i, s0); s1 = fmaf(f0.y, cs##i, s1); \
        s2 = fmaf(f1.x, cs##i, s2); s3 = fmaf(f1.y, cs##i, s3); \
        s4 = fmaf(f2.x, cs##i, s4); s5 = fmaf(f2.y, cs##i, s5); \
        s6 = fmaf(f3.x, cs##i, s6); s7 = fmaf(f3.y, cs##i, s7); }
        FOR8(SVA)
#undef SVA
        float sp = s0*s0 + s1*s1 + s2*s2 + s3*s3 + s4*s4 + s5*s5 + s6*s6 + s7*s7;
        sp += __shfl_xor(sp, 1);
        float f = sp / ((0.5f + sp) * (sqrtf(sp + 1e-6f) + 1e-6f));
#define DOTD(i) { UNP(i) \
        float dp = f0.x*s0 + f0.y*s1 + f1.x*s2 + f1.y*s3 + f2.x*s4 + f2.y*s5 + f3.x*s6 + f3.y*s7; \
        dp += __shfl_xor(dp, 1); \
        br##i = fmaf(sc##i * f, dp, br##i); }
        FOR8(DOTD)
#undef DOTD
    }

#define CF(i) float cf##i = 1.f / (1.f + __expf(-br##i));
    FOR8(CF)
#undef CF
    s0 = s1 = s2 = s3 = s4 = s5 = s6 = s7 = 0.f;
#define FS(i) { UNP(i) \
        s0 = fmaf(f0.x, cf##i, s0); s1 = fmaf(f0.y, cf##i, s1); \
        s2 = fmaf(f1.x, cf##i, s2); s3 = fmaf(f1.y, cf##i, s3); \
        s4 = fmaf(f2.x, cf##i, s4); s5 = fmaf(f2.y, cf##i, s5); \
        s6 = fmaf(f3.x, cf##i, s6); s7 = fmaf(f3.y, cf##i, s7); }
    FOR8(FS)
#undef FS
#undef UNP

    // store s fp16: [bo][px][16], own half at odh*8 (16B/lane)
    ushort* sb = sOut + ((size_t)bo * 4096 + px) * 16 + odh * 8;
    uint4 pk;
    pk.x = h2u(__floats2half2_rn(s0, s1));
    pk.y = h2u(__floats2half2_rn(s2, s3));
    pk.z = h2u(__floats2half2_rn(s4, s5));
    pk.w = h2u(__floats2half2_rn(s6, s7));
    *(uint4*)sb = pk;

    // block-level mean partial over 128 px
    sm[t][0] = s0; sm[t][1] = s1; sm[t][2] = s2; sm[t][3] = s3;
    sm[t][4] = s4; sm[t][5] = s5; sm[t][6] = s6; sm[t][7] = s7;
    __syncthreads();
    if (t < 16) {
        int oh = t >> 3, j = t & 7;
        float a = 0.f;
        for (int p = 0; p < 128; ++p) a += sm[p * 2 + oh][j];
        part[(size_t)(bo * 32 + chunk) * 16 + oh * 8 + j] = a;
    }
}

// ---------------- K4: reduce partials -> mean_hw; avg + stats ----------------
__global__ __launch_bounds__(256) void k4_avg(const ushort* __restrict__ sIn, const float* __restrict__ part,
                                              float* __restrict__ avg, float* __restrict__ stats) {
    __shared__ float mh[16];
    int bi = blockIdx.x;                 // bo*16 + chunk
    int chunk = bi & 15;
    int bo = bi >> 4;
    int t = threadIdx.x;
    int pos = chunk * 256 + t;

    if (t < 16) {
        float a = 0.f;
        for (int c = 0; c < 32; ++c) a += part[(size_t)(bo * 32 + c) * 16 + t];
        mh[t] = a * (1.f / 4096.f);
    }
    __syncthreads();

    const ushort* sb = sIn + ((size_t)bo * 4096 + pos) * 16;
    uint4 qa = *(const uint4*)&sb[0];
    uint4 qb = *(const uint4*)&sb[8];
    float2 f0 = __half22float2(u2h(qa.x)), f1 = __half22float2(u2h(qa.y));
    float2 f2 = __half22float2(u2h(qa.z)), f3 = __half22float2(u2h(qa.w));
    float2 f4 = __half22float2(u2h(qb.x)), f5 = __half22float2(u2h(qb.y));
    float2 f6 = __half22float2(u2h(qb.z)), f7 = __half22float2(u2h(qb.w));
    float a = f0.x * mh[0] + f0.y * mh[1] + f1.x * mh[2] + f1.y * mh[3]
            + f2.x * mh[4] + f2.y * mh[5] + f3.x * mh[6] + f3.y * mh[7]
            + f4.x * mh[8] + f4.y * mh[9] + f5.x * mh[10] + f5.y * mh[11]
            + f6.x * mh[12] + f6.y * mh[13] + f7.x * mh[14] + f7.y * mh[15];
    avg[(size_t)bo * 4096 + pos] = a;

    float p1 = a, p2 = a * a;
#pragma unroll
    for (int m = 1; m < 64; m <<= 1) {
        p1 += __shfl_xor(p1, m);
        p2 += __shfl_xor(p2, m);
    }
    if ((t & 63) == 0) {
        atomicAdd(&stats[bo * 2],     p1);
        atomicAdd(&stats[bo * 2 + 1], p2);
    }
}

// ---------------- K5: normalize, attn gate, residual ----------------
__global__ __launch_bounds__(256) void k5_out(const ushort* __restrict__ sIn, const float* __restrict__ x,
                                              const float* __restrict__ avg, const float* __restrict__ stats,
                                              const float* __restrict__ aw, const float* __restrict__ ab,
                                              float* __restrict__ out) {
    int bi = blockIdx.x;                 // bo*16 + chunk
    int chunk = bi & 15;
    int bo = bi >> 4;
    int oc = bo & 7;
    int pos = chunk * 256 + threadIdx.x;

    float sum = stats[bo * 2], sumsq = stats[bo * 2 + 1];
    float m   = sum * (1.f / 4096.f);
    float var = (sumsq - 4096.f * m * m) * (1.f / 4095.f);
    float sd  = sqrtf(fmaxf(var, 0.f)) + 1e-6f;

    float t   = (avg[(size_t)bo * 4096 + pos] - m) / sd * aw[oc] + ab[oc];
    float sig = 1.f / (1.f + __expf(-t));

    const ushort* sb = sIn + ((size_t)bo * 4096 + pos) * 16;
    uint4 qa = *(const uint4*)&sb[0];
    uint4 qb = *(const uint4*)&sb[8];
    float2 f0 = __half22float2(u2h(qa.x)), f1 = __half22float2(u2h(qa.y));
    float2 f2 = __half22float2(u2h(qa.z)), f3 = __half22float2(u2h(qa.w));
    float2 f4 = __half22float2(u2h(qb.x)), f5 = __half22float2(u2h(qb.y));
    float2 f6 = __half22float2(u2h(qb.z)), f7 = __half22float2(u2h(qb.w));
    float sv[16] = {f0.x, f0.y, f1.x, f1.y, f2.x, f2.y, f3.x, f3.y,
                    f4.x, f4.y, f5.x, f5.y, f6.x, f6.y, f7.x, f7.y};

    const float* xb = x + (size_t)bo * 16 * HW + pos;
    float* ob = out + (size_t)bo * 16 * HW + pos;
#pragma unroll
    for (int od = 0; od < 16; ++od) ob[od * HW] = fmaf(sv[od], sig, xb[od * HW]);
}

extern "C" void kernel_launch(void* const* d_in, const int* in_sizes, int n_in,
                              void* d_out, int out_size, void* d_ws, size_t ws_size,
                              hipStream_t stream) {
    const float* x  = (const float*)d_in[0];
    const float* w1 = (const float*)d_in[1];
    const float* b1 = (const float*)d_in[2];
    const float* w2 = (const float*)d_in[3];
    const float* b2 = (const float*)d_in[4];
    const float* w3 = (const float*)d_in[5];
    const float* b3 = (const float*)d_in[6];
    const float* aw = (const float*)d_in[7];
    const float* ab = (const float*)d_in[8];

    float* ws      = (float*)d_ws;
    ushort* h1g    = (ushort*)ws;                    // 8.4M halfs (16MB); dead after k2
    ushort* h2g    = (ushort*)(ws + 4194304);        // 8.4M halfs (16MB)
    ushort* sbuf   = (ushort*)(ws + 8388608);        // 4.2M halfs (8.4MB) [64][4096][16] fp16
    float* avg     = ws + 8388608 + 2097152;         // 262,144 floats
    float* part    = avg + 262144;                   // 32,768
    float* stats   = part + 32768;                   // 128
    ushort* w3h    = (ushort*)(stats + 128);         // 32,768 halfs
    ushort* w2f    = w3h + 32768;                    // 73,728 halfs
    float* endSmall = (float*)(w2f + 73728);         // ~44 MB mark
    ushort* ugBig  = (ushort*)endSmall;              // full u: 33,554,432 halfs (64MB)

    size_t needBig = ((char*)(ugBig + 33554432)) - (char*)d_ws;
    bool big = ws_size >= needBig;

    hipMemsetAsync(stats, 0, 128 * sizeof(float), stream);
    k0b_w3h <<<128, 256, 0, stream>>>(w3, w3h);
    k0c_w2f <<<288, 256, 0, stream>>>(w2, w2f);
    k1_conv1<<<1024, 256, 0, stream>>>(x, w1, b1, h1g);
    k2_conv2<<<4096, 256, 0, stream>>>(h1g, w2f, b2, h2g);
    if (big) {
        k3a_conv3<<<2048, 512, 0, stream>>>(h2g, w3h, b3, ugBig, 0);
        k3b_route<<<2048, 256, 0, stream>>>(ugBig, sbuf, part, 0);
    } else {
        ushort* ug = h1g;   // 16MB chunk area (h1g dead after k2)
        for (int base_b = 0; base_b < 8; base_b += 2) {
            k3a_conv3<<<512, 512, 0, stream>>>(h2g, w3h, b3, ug, base_b);
            k3b_route<<<512, 256, 0, stream>>>(ug, sbuf, part, base_b);
        }
    }
    k4_avg  <<<1024, 256, 0, stream>>>(sbuf, part, avg, stats);
    k5_out  <<<1024, 256, 0, stream>>>(sbuf, x, avg, stats, aw, ab, (float*)d_out);
}

// Round 12
// 104.469 us; speedup vs baseline: 1.6375x; 1.1321x over previous
//
#include <hip/hip_runtime.h>
#include <hip/hip_bf16.h>
#include <hip/hip_fp16.h>

#define HW 4096

typedef _Float16 f16x8 __attribute__((ext_vector_type(8)));
typedef float f32x4 __attribute__((ext_vector_type(4)));

#define FOR8(X) X(0) X(1) X(2) X(3) X(4) X(5) X(6) X(7)

static __device__ __forceinline__ __half2 u2h(unsigned int u) {
    union { unsigned int u; __half2 h; } c; c.u = u; return c.h;
}
static __device__ __forceinline__ unsigned int h2u(__half2 h) {
    union { unsigned int u; __half2 h; } c; c.h = h; return c.u;
}
static __device__ __forceinline__ f16x8 uint4_as_f16x8(uint4 v) {
    union { uint4 u; f16x8 f; } c; c.u = v; return c.f;
}

// ---------------- K0b: w3 -> fp16 MFMA A-fragment order (HW-verified R4) ----------------
__global__ __launch_bounds__(256) void k0b_w3h(const float* __restrict__ w3, ushort* __restrict__ w3h) {
    int gi = blockIdx.x * 256 + threadIdx.x;       // 64*64*8 = 32768
    if (gi >= 32768) return;
    int j = gi & 7;
    int l = (gi >> 3) & 63;
    int p = gi >> 9;                                // ic*8+oc
    int ic = p >> 3, oc = p & 7;
    int od = l & 15;
    int m  = ((l >> 4) << 3) + j;
    __half h = __float2half(w3[(size_t)((ic * 128 + oc * 16 + od) * 32 + m)]);
    w3h[gi] = __half_as_ushort(h);
}

// ---------------- K0c: w2 -> fp16 MFMA A-fragment order ----------------
__global__ __launch_bounds__(256) void k0c_w2f(const float* __restrict__ w2, ushort* __restrict__ w2f) {
    int gi = blockIdx.x * 256 + threadIdx.x;       // 8*9*2*64*8 = 73728
    if (gi >= 73728) return;
    int j   = gi & 7;
    int l   = (gi >> 3) & 63;
    int h   = (gi >> 9) & 1;
    int tap = (gi >> 10) % 9;
    int g   = gi / 9216;
    int co = h * 16 + (l & 15);
    int ci = ((l >> 4) << 3) + j;
    float v = w2[(size_t)((g * 32 + co) * 32 + ci) * 9 + tap];
    w2f[gi] = __half_as_ushort(__float2half(v));
}

// ---------------- K1: relu(x) -> 1x1 conv -> relu -> h1g fp16 [b][g][px][32] ----------------
__global__ __launch_bounds__(256) void k1_conv1(const float* __restrict__ x, const float* __restrict__ w1,
                                                const float* __restrict__ b1, ushort* __restrict__ h1g) {
    int bi = blockIdx.x;                 // ((b*8 + g)*16 + chunk)
    int chunk = bi & 15;
    int g = (bi >> 4) & 7;
    int b = bi >> 7;
    int pos = chunk * 256 + threadIdx.x;

    const float* xb = x + (size_t)(b * 128 + g * 16) * HW + pos;
    float xv[16];
#pragma unroll
    for (int i = 0; i < 16; ++i) xv[i] = fmaxf(xb[i * HW], 0.f);

    const float* wg = w1 + g * 32 * 16;
    const float* bg = b1 + g * 32;
    ushort hv[32];
#pragma unroll
    for (int m = 0; m < 32; ++m) {
        float acc = bg[m];
#pragma unroll
        for (int i = 0; i < 16; ++i) acc = fmaf(xv[i], wg[m * 16 + i], acc);
        hv[m] = __half_as_ushort(__float2half(fmaxf(acc, 0.f)));
    }
    ushort* hb = h1g + ((size_t)(b * 8 + g) * HW + pos) * 32;
#pragma unroll
    for (int q = 0; q < 4; ++q) *(uint4*)&hb[q * 8] = *(uint4*)&hv[q * 8];
}

// ---------------- K2: grouped 3x3 SAME conv via MFMA (9 shifted 1x1 GEMMs), no LDS ----------------
__global__ __launch_bounds__(256) void k2_conv2(const ushort* __restrict__ h1g, const ushort* __restrict__ w2f,
                                                const float* __restrict__ b2, ushort* __restrict__ h2g) {
    int bi = blockIdx.x;                 // b*512 + g*64 + pt
    int pt = bi & 63;
    int g  = (bi >> 6) & 7;
    int b  = bi >> 9;
    int t  = threadIdx.x;
    int w  = t >> 6, l = t & 63;
    int pxbase = pt * 64 + w * 16;
    int kgrp = l >> 4;

    int y = pxbase >> 6;
    int x = (pxbase & 63) + (l & 15);

    const ushort* hbase = h1g + (size_t)(b * 8 + g) * HW * 32;
    f16x8 Bf[9];
#pragma unroll
    for (int dy = -1; dy <= 1; ++dy) {
        int yy = y + dy;
        int yyc = yy < 0 ? 0 : (yy > 63 ? 63 : yy);
        bool rv = (yy >= 0) && (yy < 64);
#pragma unroll
        for (int dx = -1; dx <= 1; ++dx) {
            int xx = x + dx;
            int xc = xx < 0 ? 0 : (xx > 63 ? 63 : xx);
            uint4 v = *(const uint4*)&hbase[((yyc << 6) + xc) * 32 + kgrp * 8];
            bool ok = rv && (xx >= 0) && (xx < 64);
            v.x = ok ? v.x : 0u; v.y = ok ? v.y : 0u;
            v.z = ok ? v.z : 0u; v.w = ok ? v.w : 0u;
            Bf[(dy + 1) * 3 + (dx + 1)] = uint4_as_f16x8(v);
        }
    }

    const ushort* wg = w2f + (size_t)g * 9216;     // [tap][h][64][8]
    f16x8 Af[9][2];
#pragma unroll
    for (int tap = 0; tap < 9; ++tap)
#pragma unroll
        for (int h = 0; h < 2; ++h)
            Af[tap][h] = *(const f16x8*)&wg[((tap * 2 + h) * 64 + l) * 8];

    f32x4 acc[2];
#pragma unroll
    for (int h = 0; h < 2; ++h) {
        float4 bias = *(const float4*)(b2 + g * 32 + h * 16 + kgrp * 4);
        acc[h][0] = bias.x; acc[h][1] = bias.y; acc[h][2] = bias.z; acc[h][3] = bias.w;
    }
#pragma unroll
    for (int tap = 0; tap < 9; ++tap) {
#pragma unroll
        for (int h = 0; h < 2; ++h)
            acc[h] = __builtin_amdgcn_mfma_f32_16x16x32_f16(Af[tap][h], Bf[tap], acc[h], 0, 0, 0);
    }

    int px = pxbase + (l & 15);
    ushort* ob = h2g + ((size_t)(b * 8 + g) * HW + px) * 32;
#pragma unroll
    for (int h = 0; h < 2; ++h) {
        __half2 lo = __floats2half2_rn(fmaxf(acc[h][0], 0.f), fmaxf(acc[h][1], 0.f));
        __half2 hi = __floats2half2_rn(fmaxf(acc[h][2], 0.f), fmaxf(acc[h][3], 0.f));
        uint2 wv; wv.x = h2u(lo); wv.y = h2u(hi);
        *(uint2*)&ob[h * 16 + kgrp * 4] = wv;
    }
}

// ---------------- K3f: fused conv3 MFMA + routing; u lives in LDS only ----------------
// 512 thr = 8 waves, 32 px per block (one b). Phase A: wave = ic, u -> LDS
// [px][(ic*128+oc*16+od) ^ ((px&15)<<3)] fp16 (64 KB). Phase B: thread =
// (px=t>>4, oc=(t>>1)&7, odh=t&1), k3b's spill-free named-uint4 routing,
// pair reductions via shfl_xor(.,1). s staged back into dead u region,
// coalesced writeout; mean partial via wave-shfl + 4KB LDS (no atomics).
__global__ __launch_bounds__(512) void k3f_route(const ushort* __restrict__ h2g, const ushort* __restrict__ w3h,
                                                 const float* __restrict__ b3, ushort* __restrict__ sOut,
                                                 float* __restrict__ part) {
    __shared__ ushort us[32 * 1024];
    __shared__ float wred[8][16][8];
    int bid = blockIdx.x;               // b*128 + tile
    int b   = bid >> 7;
    int px0 = (bid & 127) << 5;
    int t   = threadIdx.x;
    int w   = t >> 6, l = t & 63;

    // ---- phase A: conv3 MFMA, wave = ic ----
    {
        int ic = w;
        int lrow = l & 15, lk = l >> 4;
        f16x8 bf0 = *(const f16x8*)&h2g[(((size_t)(b * 8 + ic)) * HW + px0 + lrow) * 32 + lk * 8];
        f16x8 bf1 = *(const f16x8*)&h2g[(((size_t)(b * 8 + ic)) * HW + px0 + 16 + lrow) * 32 + lk * 8];
        int s0sw = (lrow & 15) << 3;
#pragma unroll
        for (int oc = 0; oc < 8; ++oc) {
            f16x8 af = *(const f16x8*)&w3h[((ic * 8 + oc) * 64 + l) * 8];
            float4 bv = *(const float4*)(b3 + ic * 128 + oc * 16 + lk * 4);
            f32x4 c0; c0[0] = bv.x; c0[1] = bv.y; c0[2] = bv.z; c0[3] = bv.w;
            int ch = ic * 128 + oc * 16 + lk * 4;
            f32x4 d0 = __builtin_amdgcn_mfma_f32_16x16x32_f16(af, bf0, c0, 0, 0, 0);
            uint2 wv0;
            wv0.x = h2u(__floats2half2_rn(d0[0], d0[1]));
            wv0.y = h2u(__floats2half2_rn(d0[2], d0[3]));
            *(uint2*)&us[lrow * 1024 + (ch ^ s0sw)] = wv0;
            f32x4 d1 = __builtin_amdgcn_mfma_f32_16x16x32_f16(af, bf1, c0, 0, 0, 0);
            uint2 wv1;
            wv1.x = h2u(__floats2half2_rn(d1[0], d1[1]));
            wv1.y = h2u(__floats2half2_rn(d1[2], d1[3]));
            *(uint2*)&us[(16 + lrow) * 1024 + (ch ^ s0sw)] = wv1;
        }
    }
    __syncthreads();

    // ---- phase B: routing ----
    int px  = t >> 4;             // 0..31 (local)
    int oc  = (t >> 1) & 7;
    int odh = t & 1;
    int ssw = (px & 15) << 3;
    const ushort* ur = &us[px * 1024];
#define LDQ(i) uint4 q##i = *(const uint4*)&ur[((i) * 128 + oc * 16 + odh * 8) ^ ssw];
    FOR8(LDQ)
#undef LDQ
    __syncthreads();    // all u reads in regs before the stage region is overwritten

#define UNP(i) float2 f0 = __half22float2(u2h(q##i.x)), f1 = __half22float2(u2h(q##i.y)), \
                      f2 = __half22float2(u2h(q##i.z)), f3 = __half22float2(u2h(q##i.w));

#define SC(i) float sc##i; { UNP(i) \
        float sp = f0.x*f0.x + f0.y*f0.y + f1.x*f1.x + f1.y*f1.y \
                 + f2.x*f2.x + f2.y*f2.y + f3.x*f3.x + f3.y*f3.y; \
        sp += __shfl_xor(sp, 1); \
        sc##i = sp / ((0.5f + sp) * (sqrtf(sp + 1e-6f) + 1e-6f)); }
    FOR8(SC)
#undef SC

#define BRI(i) float br##i = 0.f;
    FOR8(BRI)
#undef BRI

    float s0, s1, s2, s3, s4, s5, s6, s7;
#pragma unroll
    for (int it = 0; it < 2; ++it) {
#define CSC(i) float cs##i = sc##i / (1.f + __expf(-br##i));
        FOR8(CSC)
#undef CSC
        s0 = s1 = s2 = s3 = s4 = s5 = s6 = s7 = 0.f;
#define SVA(i) { UNP(i) \
        s0 = fmaf(f0.x, cs##i, s0); s1 = fmaf(f0.y, cs##i, s1); \
        s2 = fmaf(f1.x, cs##i, s2); s3 = fmaf(f1.y, cs##i, s3); \
        s4 = fmaf(f2.x, cs##i, s4); s5 = fmaf(f2.y, cs##i, s5); \
        s6 = fmaf(f3.x, cs##i, s6); s7 = fmaf(f3.y, cs##i, s7); }
        FOR8(SVA)
#undef SVA
        float sp = s0*s0 + s1*s1 + s2*s2 + s3*s3 + s4*s4 + s5*s5 + s6*s6 + s7*s7;
        sp += __shfl_xor(sp, 1);
        float f = sp / ((0.5f + sp) * (sqrtf(sp + 1e-6f) + 1e-6f));
#define DOTD(i) { UNP(i) \
        float dp = f0.x*s0 + f0.y*s1 + f1.x*s2 + f1.y*s3 + f2.x*s4 + f2.y*s5 + f3.x*s6 + f3.y*s7; \
        dp += __shfl_xor(dp, 1); \
        br##i = fmaf(sc##i * f, dp, br##i); }
        FOR8(DOTD)
#undef DOTD
    }

#define CF(i) float cf##i = 1.f / (1.f + __expf(-br##i));
    FOR8(CF)
#undef CF
    s0 = s1 = s2 = s3 = s4 = s5 = s6 = s7 = 0.f;
#define FS(i) { UNP(i) \
        s0 = fmaf(f0.x, cf##i, s0); s1 = fmaf(f0.y, cf##i, s1); \
        s2 = fmaf(f1.x, cf##i, s2); s3 = fmaf(f1.y, cf##i, s3); \
        s4 = fmaf(f2.x, cf##i, s4); s5 = fmaf(f2.y, cf##i, s5); \
        s6 = fmaf(f3.x, cf##i, s6); s7 = fmaf(f3.y, cf##i, s7); }
    FOR8(FS)
#undef FS
#undef UNP

    // stage s into (dead) u region: row px, ch2 in [0,128)
    {
        uint4 pk;
        pk.x = h2u(__floats2half2_rn(s0, s1));
        pk.y = h2u(__floats2half2_rn(s2, s3));
        pk.z = h2u(__floats2half2_rn(s4, s5));
        pk.w = h2u(__floats2half2_rn(s6, s7));
        *(uint4*)&us[px * 1024 + ((oc * 16 + odh * 8) ^ ssw)] = pk;
    }

    // per-wave mean partial over the wave's 4 px (xor 16, 32 within wave)
    {
        float p0 = s0, p1 = s1, p2 = s2, p3 = s3, p4 = s4, p5 = s5, p6 = s6, p7 = s7;
#pragma unroll
        for (int m = 16; m <= 32; m <<= 1) {
            p0 += __shfl_xor(p0, m); p1 += __shfl_xor(p1, m);
            p2 += __shfl_xor(p2, m); p3 += __shfl_xor(p3, m);
            p4 += __shfl_xor(p4, m); p5 += __shfl_xor(p5, m);
            p6 += __shfl_xor(p6, m); p7 += __shfl_xor(p7, m);
        }
        if ((l & 48) == 0) {
            float* wr = wred[w][oc * 2 + odh];
            wr[0] = p0; wr[1] = p1; wr[2] = p2; wr[3] = p3;
            wr[4] = p4; wr[5] = p5; wr[6] = p6; wr[7] = p7;
        }
    }
    __syncthreads();

    // coalesced s writeout: wave w handles oc=w, 32 px x 2 halves
    {
        int oc2 = w;
        int pxw = l >> 1, half = l & 1;
        int ch2 = (oc2 * 16 + half * 8) ^ ((pxw & 15) << 3);
        uint4 v = *(const uint4*)&us[pxw * 1024 + ch2];
        ushort* sb = sOut + ((size_t)(b * 8 + oc2) * 4096 + px0 + pxw) * 16 + half * 8;
        *(uint4*)sb = v;
    }
    // part writeout: reduce wred over waves
    if (t < 128) {
        int comb = t >> 3, j = t & 7;    // comb = oc*2+odh
        float a = 0.f;
#pragma unroll
        for (int ww = 0; ww < 8; ++ww) a += wred[ww][comb][j];
        int oc3 = comb >> 1, odh3 = comb & 1;
        part[((size_t)(b * 8 + oc3) * 128 + (bid & 127)) * 16 + odh3 * 8 + j] = a;
    }
}

// ---------------- K4: reduce partials -> mean_hw; avg + stats ----------------
__global__ __launch_bounds__(256) void k4_avg(const ushort* __restrict__ sIn, const float* __restrict__ part,
                                              float* __restrict__ avg, float* __restrict__ stats) {
    __shared__ float mh[16];
    int bi = blockIdx.x;                 // bo*16 + chunk
    int chunk = bi & 15;
    int bo = bi >> 4;
    int t = threadIdx.x;
    int pos = chunk * 256 + t;

    if (t < 16) {
        float a = 0.f;
        for (int c = 0; c < 128; ++c) a += part[(size_t)(bo * 128 + c) * 16 + t];
        mh[t] = a * (1.f / 4096.f);
    }
    __syncthreads();

    const ushort* sb = sIn + ((size_t)bo * 4096 + pos) * 16;
    uint4 qa = *(const uint4*)&sb[0];
    uint4 qb = *(const uint4*)&sb[8];
    float2 f0 = __half22float2(u2h(qa.x)), f1 = __half22float2(u2h(qa.y));
    float2 f2 = __half22float2(u2h(qa.z)), f3 = __half22float2(u2h(qa.w));
    float2 f4 = __half22float2(u2h(qb.x)), f5 = __half22float2(u2h(qb.y));
    float2 f6 = __half22float2(u2h(qb.z)), f7 = __half22float2(u2h(qb.w));
    float a = f0.x * mh[0] + f0.y * mh[1] + f1.x * mh[2] + f1.y * mh[3]
            + f2.x * mh[4] + f2.y * mh[5] + f3.x * mh[6] + f3.y * mh[7]
            + f4.x * mh[8] + f4.y * mh[9] + f5.x * mh[10] + f5.y * mh[11]
            + f6.x * mh[12] + f6.y * mh[13] + f7.x * mh[14] + f7.y * mh[15];
    avg[(size_t)bo * 4096 + pos] = a;

    float p1 = a, p2 = a * a;
#pragma unroll
    for (int m = 1; m < 64; m <<= 1) {
        p1 += __shfl_xor(p1, m);
        p2 += __shfl_xor(p2, m);
    }
    if ((t & 63) == 0) {
        atomicAdd(&stats[bo * 2],     p1);
        atomicAdd(&stats[bo * 2 + 1], p2);
    }
}

// ---------------- K5: normalize, attn gate, residual ----------------
__global__ __launch_bounds__(256) void k5_out(const ushort* __restrict__ sIn, const float* __restrict__ x,
                                              const float* __restrict__ avg, const float* __restrict__ stats,
                                              const float* __restrict__ aw, const float* __restrict__ ab,
                                              float* __restrict__ out) {
    int bi = blockIdx.x;                 // bo*16 + chunk
    int chunk = bi & 15;
    int bo = bi >> 4;
    int oc = bo & 7;
    int pos = chunk * 256 + threadIdx.x;

    float sum = stats[bo * 2], sumsq = stats[bo * 2 + 1];
    float m   = sum * (1.f / 4096.f);
    float var = (sumsq - 4096.f * m * m) * (1.f / 4095.f);
    float sd  = sqrtf(fmaxf(var, 0.f)) + 1e-6f;

    float t   = (avg[(size_t)bo * 4096 + pos] - m) / sd * aw[oc] + ab[oc];
    float sig = 1.f / (1.f + __expf(-t));

    const ushort* sb = sIn + ((size_t)bo * 4096 + pos) * 16;
    uint4 qa = *(const uint4*)&sb[0];
    uint4 qb = *(const uint4*)&sb[8];
    float2 f0 = __half22float2(u2h(qa.x)), f1 = __half22float2(u2h(qa.y));
    float2 f2 = __half22float2(u2h(qa.z)), f3 = __half22float2(u2h(qa.w));
    float2 f4 = __half22float2(u2h(qb.x)), f5 = __half22float2(u2h(qb.y));
    float2 f6 = __half22float2(u2h(qb.z)), f7 = __half22float2(u2h(qb.w));
    float sv[16] = {f0.x, f0.y, f1.x, f1.y, f2.x, f2.y, f3.x, f3.y,
                    f4.x, f4.y, f5.x, f5.y, f6.x, f6.y, f7.x, f7.y};

    const float* xb = x + (size_t)bo * 16 * HW + pos;
    float* ob = out + (size_t)bo * 16 * HW + pos;
#pragma unroll
    for (int od = 0; od < 16; ++od) ob[od * HW] = fmaf(sv[od], sig, xb[od * HW]);
}

extern "C" void kernel_launch(void* const* d_in, const int* in_sizes, int n_in,
                              void* d_out, int out_size, void* d_ws, size_t ws_size,
                              hipStream_t stream) {
    const float* x  = (const float*)d_in[0];
    const float* w1 = (const float*)d_in[1];
    const float* b1 = (const float*)d_in[2];
    const float* w2 = (const float*)d_in[3];
    const float* b2 = (const float*)d_in[4];
    const float* w3 = (const float*)d_in[5];
    const float* b3 = (const float*)d_in[6];
    const float* aw = (const float*)d_in[7];
    const float* ab = (const float*)d_in[8];

    float* ws      = (float*)d_ws;
    ushort* h1g    = (ushort*)ws;                    // 8.4M halfs (16MB)
    ushort* h2g    = (ushort*)(ws + 4194304);        // 8.4M halfs (16MB)
    ushort* sbuf   = (ushort*)(ws + 8388608);        // 4.2M halfs (8.4MB) [64][4096][16] fp16
    float* avg     = ws + 8388608 + 2097152;         // 262,144 floats
    float* part    = avg + 262144;                   // 131,072 floats [64][128][16]
    float* stats   = part + 131072;                  // 128
    ushort* w3h    = (ushort*)(stats + 128);         // 32,768 halfs
    ushort* w2f    = w3h + 32768;                    // 73,728 halfs
    // total ~42 MB

    hipMemsetAsync(stats, 0, 128 * sizeof(float), stream);
    k0b_w3h  <<<128, 256, 0, stream>>>(w3, w3h);
    k0c_w2f  <<<288, 256, 0, stream>>>(w2, w2f);
    k1_conv1 <<<1024, 256, 0, stream>>>(x, w1, b1, h1g);
    k2_conv2 <<<4096, 256, 0, stream>>>(h1g, w2f, b2, h2g);
    k3f_route<<<1024, 512, 0, stream>>>(h2g, w3h, b3, sbuf, part);
    k4_avg   <<<1024, 256, 0, stream>>>(sbuf, part, avg, stats);
    k5_out   <<<1024, 256, 0, stream>>>(sbuf, x, avg, stats, aw, ab, (float*)d_out);
}

// Round 13
// 94.331 us; speedup vs baseline: 1.8135x; 1.1075x over previous
//
#include <hip/hip_runtime.h>
#include <hip/hip_bf16.h>
#include <hip/hip_fp16.h>

#define HW 4096

typedef _Float16 f16x8 __attribute__((ext_vector_type(8)));
typedef float f32x4 __attribute__((ext_vector_type(4)));

#define FOR8(X) X(0) X(1) X(2) X(3) X(4) X(5) X(6) X(7)

static __device__ __forceinline__ __half2 u2h(unsigned int u) {
    union { unsigned int u; __half2 h; } c; c.u = u; return c.h;
}
static __device__ __forceinline__ unsigned int h2u(__half2 h) {
    union { unsigned int u; __half2 h; } c; c.h = h; return c.u;
}

// ---------------- K0: weight prep (w3 A-frags + w2 A-frags, merged) ----------------
__global__ __launch_bounds__(256) void k0_prep(const float* __restrict__ w3, ushort* __restrict__ w3h,
                                               const float* __restrict__ w2, ushort* __restrict__ w2f) {
    int bid = blockIdx.x;
    int t = threadIdx.x;
    if (bid < 128) {
        int gi = bid * 256 + t;                    // 32768: w3h[p][lane][j]
        int j = gi & 7;
        int l = (gi >> 3) & 63;
        int p = gi >> 9;                           // ic*8+oc
        int ic = p >> 3, oc = p & 7;
        int od = l & 15;
        int m  = ((l >> 4) << 3) + j;
        w3h[gi] = __half_as_ushort(__float2half(w3[(size_t)((ic * 128 + oc * 16 + od) * 32 + m)]));
    } else {
        int gi = (bid - 128) * 256 + t;            // 73728: w2f[g][tap][h][lane][j]
        if (gi >= 73728) return;
        int j   = gi & 7;
        int l   = (gi >> 3) & 63;
        int h   = (gi >> 9) & 1;
        int tap = (gi >> 10) % 9;
        int g   = gi / 9216;
        int co = h * 16 + (l & 15);
        int ci = ((l >> 4) << 3) + j;
        w2f[gi] = __half_as_ushort(__float2half(w2[(size_t)((g * 32 + co) * 32 + ci) * 9 + tap]));
    }
}

// ---------------- K12: fused relu->conv1->relu (LDS) -> 3x3 conv2 MFMA -> h2g ----------------
// Block = (b, g, row y); 256 thr = 4 waves. Phase 1: 198 threads compute h1 fp16 for
// rows y-1..y+1 x cols -1..64 into LDS [3][66][40] (zero outside image). Phase 2:
// k2's 9-tap MFMA with B-frags read from LDS. No h1 global buffer at all.
__global__ __launch_bounds__(256) void k12_conv(const float* __restrict__ x, const float* __restrict__ w1,
                                                const float* __restrict__ b1, const ushort* __restrict__ w2f,
                                                const float* __restrict__ b2, ushort* __restrict__ h2g) {
    __shared__ ushort h1s[3][66][40];   // stride 40 halfs = 80B: 16B-aligned, mild conflicts

    int bi = blockIdx.x;                 // b*512 + g*64 + y
    int y  = bi & 63;
    int g  = (bi >> 6) & 7;
    int b  = bi >> 9;
    int t  = threadIdx.x;

    // ---- phase 1: conv1 into LDS ----
    if (t < 198) {
        int r  = t / 66;                 // 0..2 -> row y + r - 1
        int xi = t - r * 66;             // 0..65 -> col xi - 1
        int yy = y + r - 1;
        int xx = xi - 1;
        bool valid = (yy >= 0) && (yy < 64) && (xx >= 0) && (xx < 64);
        ushort hv[32];
        if (valid) {
            const float* xb = x + (size_t)(b * 128 + g * 16) * HW + yy * 64 + xx;
            float xv[16];
#pragma unroll
            for (int i = 0; i < 16; ++i) xv[i] = fmaxf(xb[i * HW], 0.f);
            const float* wg = w1 + g * 512;
            const float* bg = b1 + g * 32;
#pragma unroll
            for (int m = 0; m < 32; ++m) {
                float acc = bg[m];
#pragma unroll
                for (int i = 0; i < 16; ++i) acc = fmaf(xv[i], wg[m * 16 + i], acc);
                hv[m] = __half_as_ushort(__float2half(fmaxf(acc, 0.f)));
            }
        } else {
#pragma unroll
            for (int m = 0; m < 32; ++m) hv[m] = 0;
        }
        ushort* dst = &h1s[r][xi][0];
#pragma unroll
        for (int q = 0; q < 4; ++q) *(uint4*)&dst[q * 8] = *(uint4*)&hv[q * 8];
    }
    __syncthreads();

    // ---- phase 2: conv2 via 9 MFMAs ----
    int w  = t >> 6, l = t & 63;
    int lrow = l & 15, kgrp = l >> 4;
    int xcol = w * 16 + lrow;            // output col 0..63

    f16x8 Bf[9];
#pragma unroll
    for (int dy = 0; dy < 3; ++dy)
#pragma unroll
        for (int dx = 0; dx < 3; ++dx)
            Bf[dy * 3 + dx] = *(const f16x8*)&h1s[dy][xcol + dx][kgrp * 8];

    const ushort* wg2 = w2f + (size_t)g * 9216;    // [tap][h][64][8]
    f16x8 Af[9][2];
#pragma unroll
    for (int tap = 0; tap < 9; ++tap)
#pragma unroll
        for (int h = 0; h < 2; ++h)
            Af[tap][h] = *(const f16x8*)&wg2[((tap * 2 + h) * 64 + l) * 8];

    f32x4 acc[2];
#pragma unroll
    for (int h = 0; h < 2; ++h) {
        float4 bias = *(const float4*)(b2 + g * 32 + h * 16 + kgrp * 4);
        acc[h][0] = bias.x; acc[h][1] = bias.y; acc[h][2] = bias.z; acc[h][3] = bias.w;
    }
#pragma unroll
    for (int tap = 0; tap < 9; ++tap) {
#pragma unroll
        for (int h = 0; h < 2; ++h)
            acc[h] = __builtin_amdgcn_mfma_f32_16x16x32_f16(Af[tap][h], Bf[tap], acc[h], 0, 0, 0);
    }

    int px = y * 64 + xcol;
    ushort* ob = h2g + ((size_t)(b * 8 + g) * HW + px) * 32;
#pragma unroll
    for (int h = 0; h < 2; ++h) {
        __half2 lo = __floats2half2_rn(fmaxf(acc[h][0], 0.f), fmaxf(acc[h][1], 0.f));
        __half2 hi = __floats2half2_rn(fmaxf(acc[h][2], 0.f), fmaxf(acc[h][3], 0.f));
        uint2 wv; wv.x = h2u(lo); wv.y = h2u(hi);
        *(uint2*)&ob[h * 16 + kgrp * 4] = wv;
    }
}

// ---------------- K3f: fused conv3 MFMA + routing; u lives in LDS only ----------------
__global__ __launch_bounds__(512) void k3f_route(const ushort* __restrict__ h2g, const ushort* __restrict__ w3h,
                                                 const float* __restrict__ b3, ushort* __restrict__ sOut,
                                                 float* __restrict__ part) {
    __shared__ ushort us[32 * 1024];
    __shared__ float wred[8][16][8];
    int bid = blockIdx.x;               // b*128 + tile
    int b   = bid >> 7;
    int px0 = (bid & 127) << 5;
    int t   = threadIdx.x;
    int w   = t >> 6, l = t & 63;

    // ---- phase A: conv3 MFMA, wave = ic ----
    {
        int ic = w;
        int lrow = l & 15, lk = l >> 4;
        f16x8 bf0 = *(const f16x8*)&h2g[(((size_t)(b * 8 + ic)) * HW + px0 + lrow) * 32 + lk * 8];
        f16x8 bf1 = *(const f16x8*)&h2g[(((size_t)(b * 8 + ic)) * HW + px0 + 16 + lrow) * 32 + lk * 8];
        int s0sw = (lrow & 15) << 3;
#pragma unroll
        for (int oc = 0; oc < 8; ++oc) {
            f16x8 af = *(const f16x8*)&w3h[((ic * 8 + oc) * 64 + l) * 8];
            float4 bv = *(const float4*)(b3 + ic * 128 + oc * 16 + lk * 4);
            f32x4 c0; c0[0] = bv.x; c0[1] = bv.y; c0[2] = bv.z; c0[3] = bv.w;
            int ch = ic * 128 + oc * 16 + lk * 4;
            f32x4 d0 = __builtin_amdgcn_mfma_f32_16x16x32_f16(af, bf0, c0, 0, 0, 0);
            uint2 wv0;
            wv0.x = h2u(__floats2half2_rn(d0[0], d0[1]));
            wv0.y = h2u(__floats2half2_rn(d0[2], d0[3]));
            *(uint2*)&us[lrow * 1024 + (ch ^ s0sw)] = wv0;
            f32x4 d1 = __builtin_amdgcn_mfma_f32_16x16x32_f16(af, bf1, c0, 0, 0, 0);
            uint2 wv1;
            wv1.x = h2u(__floats2half2_rn(d1[0], d1[1]));
            wv1.y = h2u(__floats2half2_rn(d1[2], d1[3]));
            *(uint2*)&us[(16 + lrow) * 1024 + (ch ^ s0sw)] = wv1;
        }
    }
    __syncthreads();

    // ---- phase B: routing ----
    int px  = t >> 4;             // 0..31 (local)
    int oc  = (t >> 1) & 7;
    int odh = t & 1;
    int ssw = (px & 15) << 3;
    const ushort* ur = &us[px * 1024];
#define LDQ(i) uint4 q##i = *(const uint4*)&ur[((i) * 128 + oc * 16 + odh * 8) ^ ssw];
    FOR8(LDQ)
#undef LDQ
    __syncthreads();

#define UNP(i) float2 f0 = __half22float2(u2h(q##i.x)), f1 = __half22float2(u2h(q##i.y)), \
                      f2 = __half22float2(u2h(q##i.z)), f3 = __half22float2(u2h(q##i.w));

#define SC(i) float sc##i; { UNP(i) \
        float sp = f0.x*f0.x + f0.y*f0.y + f1.x*f1.x + f1.y*f1.y \
                 + f2.x*f2.x + f2.y*f2.y + f3.x*f3.x + f3.y*f3.y; \
        sp += __shfl_xor(sp, 1); \
        sc##i = sp / ((0.5f + sp) * (sqrtf(sp + 1e-6f) + 1e-6f)); }
    FOR8(SC)
#undef SC

#define BRI(i) float br##i = 0.f;
    FOR8(BRI)
#undef BRI

    float s0, s1, s2, s3, s4, s5, s6, s7;
#pragma unroll
    for (int it = 0; it < 2; ++it) {
#define CSC(i) float cs##i = sc##i / (1.f + __expf(-br##i));
        FOR8(CSC)
#undef CSC
        s0 = s1 = s2 = s3 = s4 = s5 = s6 = s7 = 0.f;
#define SVA(i) { UNP(i) \
        s0 = fmaf(f0.x, cs##i, s0); s1 = fmaf(f0.y, cs##i, s1); \
        s2 = fmaf(f1.x, cs##i, s2); s3 = fmaf(f1.y, cs##i, s3); \
        s4 = fmaf(f2.x, cs##i, s4); s5 = fmaf(f2.y, cs##i, s5); \
        s6 = fmaf(f3.x, cs##i, s6); s7 = fmaf(f3.y, cs##i, s7); }
        FOR8(SVA)
#undef SVA
        float sp = s0*s0 + s1*s1 + s2*s2 + s3*s3 + s4*s4 + s5*s5 + s6*s6 + s7*s7;
        sp += __shfl_xor(sp, 1);
        float f = sp / ((0.5f + sp) * (sqrtf(sp + 1e-6f) + 1e-6f));
#define DOTD(i) { UNP(i) \
        float dp = f0.x*s0 + f0.y*s1 + f1.x*s2 + f1.y*s3 + f2.x*s4 + f2.y*s5 + f3.x*s6 + f3.y*s7; \
        dp += __shfl_xor(dp, 1); \
        br##i = fmaf(sc##i * f, dp, br##i); }
        FOR8(DOTD)
#undef DOTD
    }

#define CF(i) float cf##i = 1.f / (1.f + __expf(-br##i));
    FOR8(CF)
#undef CF
    s0 = s1 = s2 = s3 = s4 = s5 = s6 = s7 = 0.f;
#define FS(i) { UNP(i) \
        s0 = fmaf(f0.x, cf##i, s0); s1 = fmaf(f0.y, cf##i, s1); \
        s2 = fmaf(f1.x, cf##i, s2); s3 = fmaf(f1.y, cf##i, s3); \
        s4 = fmaf(f2.x, cf##i, s4); s5 = fmaf(f2.y, cf##i, s5); \
        s6 = fmaf(f3.x, cf##i, s6); s7 = fmaf(f3.y, cf##i, s7); }
    FOR8(FS)
#undef FS
#undef UNP

    {
        uint4 pk;
        pk.x = h2u(__floats2half2_rn(s0, s1));
        pk.y = h2u(__floats2half2_rn(s2, s3));
        pk.z = h2u(__floats2half2_rn(s4, s5));
        pk.w = h2u(__floats2half2_rn(s6, s7));
        *(uint4*)&us[px * 1024 + ((oc * 16 + odh * 8) ^ ssw)] = pk;
    }

    {
        float p0 = s0, p1 = s1, p2 = s2, p3 = s3, p4 = s4, p5 = s5, p6 = s6, p7 = s7;
#pragma unroll
        for (int m = 16; m <= 32; m <<= 1) {
            p0 += __shfl_xor(p0, m); p1 += __shfl_xor(p1, m);
            p2 += __shfl_xor(p2, m); p3 += __shfl_xor(p3, m);
            p4 += __shfl_xor(p4, m); p5 += __shfl_xor(p5, m);
            p6 += __shfl_xor(p6, m); p7 += __shfl_xor(p7, m);
        }
        if ((l & 48) == 0) {
            float* wr = wred[w][oc * 2 + odh];
            wr[0] = p0; wr[1] = p1; wr[2] = p2; wr[3] = p3;
            wr[4] = p4; wr[5] = p5; wr[6] = p6; wr[7] = p7;
        }
    }
    __syncthreads();

    {
        int oc2 = w;
        int pxw = l >> 1, half = l & 1;
        int ch2 = (oc2 * 16 + half * 8) ^ ((pxw & 15) << 3);
        uint4 v = *(const uint4*)&us[pxw * 1024 + ch2];
        ushort* sb = sOut + ((size_t)(b * 8 + oc2) * 4096 + px0 + pxw) * 16 + half * 8;
        *(uint4*)sb = v;
    }
    if (t < 128) {
        int comb = t >> 3, j = t & 7;
        float a = 0.f;
#pragma unroll
        for (int ww = 0; ww < 8; ++ww) a += wred[ww][comb][j];
        int oc3 = comb >> 1, odh3 = comb & 1;
        part[((size_t)(b * 8 + oc3) * 128 + (bid & 127)) * 16 + odh3 * 8 + j] = a;
    }
}

// ---------------- K4: reduce partials -> mean_hw; avg + stats ----------------
__global__ __launch_bounds__(256) void k4_avg(const ushort* __restrict__ sIn, const float* __restrict__ part,
                                              float* __restrict__ avg, float* __restrict__ stats) {
    __shared__ float mh[16];
    int bi = blockIdx.x;                 // bo*16 + chunk
    int chunk = bi & 15;
    int bo = bi >> 4;
    int t = threadIdx.x;
    int pos = chunk * 256 + t;

    if (t < 16) {
        float a = 0.f;
        for (int c = 0; c < 128; ++c) a += part[(size_t)(bo * 128 + c) * 16 + t];
        mh[t] = a * (1.f / 4096.f);
    }
    __syncthreads();

    const ushort* sb = sIn + ((size_t)bo * 4096 + pos) * 16;
    uint4 qa = *(const uint4*)&sb[0];
    uint4 qb = *(const uint4*)&sb[8];
    float2 f0 = __half22float2(u2h(qa.x)), f1 = __half22float2(u2h(qa.y));
    float2 f2 = __half22float2(u2h(qa.z)), f3 = __half22float2(u2h(qa.w));
    float2 f4 = __half22float2(u2h(qb.x)), f5 = __half22float2(u2h(qb.y));
    float2 f6 = __half22float2(u2h(qb.z)), f7 = __half22float2(u2h(qb.w));
    float a = f0.x * mh[0] + f0.y * mh[1] + f1.x * mh[2] + f1.y * mh[3]
            + f2.x * mh[4] + f2.y * mh[5] + f3.x * mh[6] + f3.y * mh[7]
            + f4.x * mh[8] + f4.y * mh[9] + f5.x * mh[10] + f5.y * mh[11]
            + f6.x * mh[12] + f6.y * mh[13] + f7.x * mh[14] + f7.y * mh[15];
    avg[(size_t)bo * 4096 + pos] = a;

    float p1 = a, p2 = a * a;
#pragma unroll
    for (int m = 1; m < 64; m <<= 1) {
        p1 += __shfl_xor(p1, m);
        p2 += __shfl_xor(p2, m);
    }
    if ((t & 63) == 0) {
        atomicAdd(&stats[bo * 2],     p1);
        atomicAdd(&stats[bo * 2 + 1], p2);
    }
}

// ---------------- K5: normalize, attn gate, residual ----------------
__global__ __launch_bounds__(256) void k5_out(const ushort* __restrict__ sIn, const float* __restrict__ x,
                                              const float* __restrict__ avg, const float* __restrict__ stats,
                                              const float* __restrict__ aw, const float* __restrict__ ab,
                                              float* __restrict__ out) {
    int bi = blockIdx.x;                 // bo*16 + chunk
    int chunk = bi & 15;
    int bo = bi >> 4;
    int oc = bo & 7;
    int pos = chunk * 256 + threadIdx.x;

    float sum = stats[bo * 2], sumsq = stats[bo * 2 + 1];
    float m   = sum * (1.f / 4096.f);
    float var = (sumsq - 4096.f * m * m) * (1.f / 4095.f);
    float sd  = sqrtf(fmaxf(var, 0.f)) + 1e-6f;

    float t   = (avg[(size_t)bo * 4096 + pos] - m) / sd * aw[oc] + ab[oc];
    float sig = 1.f / (1.f + __expf(-t));

    const ushort* sb = sIn + ((size_t)bo * 4096 + pos) * 16;
    uint4 qa = *(const uint4*)&sb[0];
    uint4 qb = *(const uint4*)&sb[8];
    float2 f0 = __half22float2(u2h(qa.x)), f1 = __half22float2(u2h(qa.y));
    float2 f2 = __half22float2(u2h(qa.z)), f3 = __half22float2(u2h(qa.w));
    float2 f4 = __half22float2(u2h(qb.x)), f5 = __half22float2(u2h(qb.y));
    float2 f6 = __half22float2(u2h(qb.z)), f7 = __half22float2(u2h(qb.w));
    float sv[16] = {f0.x, f0.y, f1.x, f1.y, f2.x, f2.y, f3.x, f3.y,
                    f4.x, f4.y, f5.x, f5.y, f6.x, f6.y, f7.x, f7.y};

    const float* xb = x + (size_t)bo * 16 * HW + pos;
    float* ob = out + (size_t)bo * 16 * HW + pos;
#pragma unroll
    for (int od = 0; od < 16; ++od) ob[od * HW] = fmaf(sv[od], sig, xb[od * HW]);
}

extern "C" void kernel_launch(void* const* d_in, const int* in_sizes, int n_in,
                              void* d_out, int out_size, void* d_ws, size_t ws_size,
                              hipStream_t stream) {
    const float* x  = (const float*)d_in[0];
    const float* w1 = (const float*)d_in[1];
    const float* b1 = (const float*)d_in[2];
    const float* w2 = (const float*)d_in[3];
    const float* b2 = (const float*)d_in[4];
    const float* w3 = (const float*)d_in[5];
    const float* b3 = (const float*)d_in[6];
    const float* aw = (const float*)d_in[7];
    const float* ab = (const float*)d_in[8];

    float* ws      = (float*)d_ws;
    ushort* h2g    = (ushort*)ws;                    // 8.4M halfs (16MB)
    ushort* sbuf   = (ushort*)(ws + 4194304);        // 4.2M halfs (8.4MB) [64][4096][16] fp16
    float* avg     = ws + 4194304 + 2097152;         // 262,144 floats
    float* part    = avg + 262144;                   // 131,072 floats [64][128][16]
    float* stats   = part + 131072;                  // 128
    ushort* w3h    = (ushort*)(stats + 128);         // 32,768 halfs
    ushort* w2f    = w3h + 32768;                    // 73,728 halfs
    // total ~26 MB

    hipMemsetAsync(stats, 0, 128 * sizeof(float), stream);
    k0_prep  <<<416, 256, 0, stream>>>(w3, w3h, w2, w2f);
    k12_conv <<<4096, 256, 0, stream>>>(x, w1, b1, w2f, b2, h2g);
    k3f_route<<<1024, 512, 0, stream>>>(h2g, w3h, b3, sbuf, part);
    k4_avg   <<<1024, 256, 0, stream>>>(sbuf, part, avg, stats);
    k5_out   <<<1024, 256, 0, stream>>>(sbuf, x, avg, stats, aw, ab, (float*)d_out);
}

// Round 14
// 85.635 us; speedup vs baseline: 1.9977x; 1.1016x over previous
//
#include <hip/hip_runtime.h>
#include <hip/hip_bf16.h>
#include <hip/hip_fp16.h>

#define HW 4096

typedef _Float16 f16x8 __attribute__((ext_vector_type(8)));
typedef float f32x4 __attribute__((ext_vector_type(4)));

#define FOR8(X) X(0) X(1) X(2) X(3) X(4) X(5) X(6) X(7)

static __device__ __forceinline__ __half2 u2h(unsigned int u) {
    union { unsigned int u; __half2 h; } c; c.u = u; return c.h;
}
static __device__ __forceinline__ unsigned int h2u(__half2 h) {
    union { unsigned int u; __half2 h; } c; c.h = h; return c.u;
}

// ---------------- K0: weight prep (w3 A-frags + w2 A-frags + stats zero) ----------------
__global__ __launch_bounds__(256) void k0_prep(const float* __restrict__ w3, ushort* __restrict__ w3h,
                                               const float* __restrict__ w2, ushort* __restrict__ w2f,
                                               float* __restrict__ stats) {
    int bid = blockIdx.x;
    int t = threadIdx.x;
    if (bid == 0 && t < 128) stats[t] = 0.f;
    if (bid < 128) {
        int gi = bid * 256 + t;                    // 32768: w3h[p][lane][j]
        int j = gi & 7;
        int l = (gi >> 3) & 63;
        int p = gi >> 9;                           // ic*8+oc
        int ic = p >> 3, oc = p & 7;
        int od = l & 15;
        int m  = ((l >> 4) << 3) + j;
        w3h[gi] = __half_as_ushort(__float2half(w3[(size_t)((ic * 128 + oc * 16 + od) * 32 + m)]));
    } else {
        int gi = (bid - 128) * 256 + t;            // 73728: w2f[g][tap][h][lane][j]
        if (gi >= 73728) return;
        int j   = gi & 7;
        int l   = (gi >> 3) & 63;
        int h   = (gi >> 9) & 1;
        int tap = (gi >> 10) % 9;
        int g   = gi / 9216;
        int co = h * 16 + (l & 15);
        int ci = ((l >> 4) << 3) + j;
        w2f[gi] = __half_as_ushort(__float2half(w2[(size_t)((g * 32 + co) * 32 + ci) * 9 + tap]));
    }
}

// ---------------- K12: fused conv1(LDS) + 3x3 conv2 MFMA, 4-row tiles ----------------
// Block = (b, g, row-quad q); 256 thr = 4 waves. Phase 1: 396 slots (6 halo rows x 66
// cols) of h1 fp16 into LDS [6][66][40] (loop, 2 rounds). Phase 2: wave = output row,
// 4 MFMA tiles of 16 px; A-frags per-tap from L1 (low VGPR, no spill risk).
__global__ __launch_bounds__(256) void k12_conv(const float* __restrict__ x, const float* __restrict__ w1,
                                                const float* __restrict__ b1, const ushort* __restrict__ w2f,
                                                const float* __restrict__ b2, ushort* __restrict__ h2g) {
    __shared__ ushort h1s[6][66][40];   // 31.7 KB; stride 40 halfs keeps 16B alignment

    int bi = blockIdx.x;                 // b*128 + g*16 + q
    int q  = bi & 15;
    int g  = (bi >> 4) & 7;
    int b  = bi >> 7;
    int y0 = q * 4;
    int t  = threadIdx.x;

    // ---- phase 1: conv1 into LDS (rows y0-1 .. y0+4) ----
    for (int i = t; i < 396; i += 256) {
        int r  = i / 66;                 // 0..5
        int xi = i - r * 66;             // 0..65 -> col xi-1
        int yy = y0 + r - 1;
        int xx = xi - 1;
        bool valid = (yy >= 0) && (yy < 64) && (xx >= 0) && (xx < 64);
        ushort hv[32];
        if (valid) {
            const float* xb = x + (size_t)(b * 128 + g * 16) * HW + yy * 64 + xx;
            float xv[16];
#pragma unroll
            for (int i2 = 0; i2 < 16; ++i2) xv[i2] = fmaxf(xb[i2 * HW], 0.f);
            const float* wg = w1 + g * 512;
            const float* bg = b1 + g * 32;
#pragma unroll
            for (int m = 0; m < 32; ++m) {
                float acc = bg[m];
#pragma unroll
                for (int i2 = 0; i2 < 16; ++i2) acc = fmaf(xv[i2], wg[m * 16 + i2], acc);
                hv[m] = __half_as_ushort(__float2half(fmaxf(acc, 0.f)));
            }
        } else {
#pragma unroll
            for (int m = 0; m < 32; ++m) hv[m] = 0;
        }
        ushort* dst = &h1s[r][xi][0];
#pragma unroll
        for (int q2 = 0; q2 < 4; ++q2) *(uint4*)&dst[q2 * 8] = *(uint4*)&hv[q2 * 8];
    }
    __syncthreads();

    // ---- phase 2: conv2 via MFMA; wave w = row y0+w, 4 tiles of 16 px ----
    int w  = t >> 6, l = t & 63;
    int lrow = l & 15, kgrp = l >> 4;
    int yloc = w;
    const ushort* wg2 = w2f + (size_t)g * 9216;    // [tap][h][64][8]

    float4 bias0 = *(const float4*)(b2 + g * 32 + kgrp * 4);
    float4 bias1 = *(const float4*)(b2 + g * 32 + 16 + kgrp * 4);

#pragma unroll
    for (int tile = 0; tile < 4; ++tile) {
        int xcol = tile * 16 + lrow;
        f32x4 acc0, acc1;
        acc0[0] = bias0.x; acc0[1] = bias0.y; acc0[2] = bias0.z; acc0[3] = bias0.w;
        acc1[0] = bias1.x; acc1[1] = bias1.y; acc1[2] = bias1.z; acc1[3] = bias1.w;
#pragma unroll
        for (int tap = 0; tap < 9; ++tap) {
            int dy = tap / 3, dx = tap - dy * 3;
            f16x8 Bf = *(const f16x8*)&h1s[yloc + dy][xcol + dx][kgrp * 8];
            f16x8 A0 = *(const f16x8*)&wg2[((tap * 2 + 0) * 64 + l) * 8];
            f16x8 A1 = *(const f16x8*)&wg2[((tap * 2 + 1) * 64 + l) * 8];
            acc0 = __builtin_amdgcn_mfma_f32_16x16x32_f16(A0, Bf, acc0, 0, 0, 0);
            acc1 = __builtin_amdgcn_mfma_f32_16x16x32_f16(A1, Bf, acc1, 0, 0, 0);
        }
        int px = (y0 + yloc) * 64 + xcol;
        ushort* ob = h2g + ((size_t)(b * 8 + g) * HW + px) * 32;
        uint2 wv0, wv1;
        wv0.x = h2u(__floats2half2_rn(fmaxf(acc0[0], 0.f), fmaxf(acc0[1], 0.f)));
        wv0.y = h2u(__floats2half2_rn(fmaxf(acc0[2], 0.f), fmaxf(acc0[3], 0.f)));
        wv1.x = h2u(__floats2half2_rn(fmaxf(acc1[0], 0.f), fmaxf(acc1[1], 0.f)));
        wv1.y = h2u(__floats2half2_rn(fmaxf(acc1[2], 0.f), fmaxf(acc1[3], 0.f)));
        *(uint2*)&ob[kgrp * 4] = wv0;
        *(uint2*)&ob[16 + kgrp * 4] = wv1;
    }
}

// ---------------- K3f: fused conv3 MFMA + routing; u lives in LDS only ----------------
__global__ __launch_bounds__(512) void k3f_route(const ushort* __restrict__ h2g, const ushort* __restrict__ w3h,
                                                 const float* __restrict__ b3, ushort* __restrict__ sOut,
                                                 float* __restrict__ part) {
    __shared__ ushort us[32 * 1024];
    __shared__ float wred[8][16][8];
    int bid = blockIdx.x;               // b*128 + tile
    int b   = bid >> 7;
    int px0 = (bid & 127) << 5;
    int t   = threadIdx.x;
    int w   = t >> 6, l = t & 63;

    // ---- phase A: conv3 MFMA, wave = ic ----
    {
        int ic = w;
        int lrow = l & 15, lk = l >> 4;
        f16x8 bf0 = *(const f16x8*)&h2g[(((size_t)(b * 8 + ic)) * HW + px0 + lrow) * 32 + lk * 8];
        f16x8 bf1 = *(const f16x8*)&h2g[(((size_t)(b * 8 + ic)) * HW + px0 + 16 + lrow) * 32 + lk * 8];
        int s0sw = (lrow & 15) << 3;
#pragma unroll
        for (int oc = 0; oc < 8; ++oc) {
            f16x8 af = *(const f16x8*)&w3h[((ic * 8 + oc) * 64 + l) * 8];
            float4 bv = *(const float4*)(b3 + ic * 128 + oc * 16 + lk * 4);
            f32x4 c0; c0[0] = bv.x; c0[1] = bv.y; c0[2] = bv.z; c0[3] = bv.w;
            int ch = ic * 128 + oc * 16 + lk * 4;
            f32x4 d0 = __builtin_amdgcn_mfma_f32_16x16x32_f16(af, bf0, c0, 0, 0, 0);
            uint2 wv0;
            wv0.x = h2u(__floats2half2_rn(d0[0], d0[1]));
            wv0.y = h2u(__floats2half2_rn(d0[2], d0[3]));
            *(uint2*)&us[lrow * 1024 + (ch ^ s0sw)] = wv0;
            f32x4 d1 = __builtin_amdgcn_mfma_f32_16x16x32_f16(af, bf1, c0, 0, 0, 0);
            uint2 wv1;
            wv1.x = h2u(__floats2half2_rn(d1[0], d1[1]));
            wv1.y = h2u(__floats2half2_rn(d1[2], d1[3]));
            *(uint2*)&us[(16 + lrow) * 1024 + (ch ^ s0sw)] = wv1;
        }
    }
    __syncthreads();

    // ---- phase B: routing ----
    int px  = t >> 4;
    int oc  = (t >> 1) & 7;
    int odh = t & 1;
    int ssw = (px & 15) << 3;
    const ushort* ur = &us[px * 1024];
#define LDQ(i) uint4 q##i = *(const uint4*)&ur[((i) * 128 + oc * 16 + odh * 8) ^ ssw];
    FOR8(LDQ)
#undef LDQ
    __syncthreads();

#define UNP(i) float2 f0 = __half22float2(u2h(q##i.x)), f1 = __half22float2(u2h(q##i.y)), \
                      f2 = __half22float2(u2h(q##i.z)), f3 = __half22float2(u2h(q##i.w));

#define SC(i) float sc##i; { UNP(i) \
        float sp = f0.x*f0.x + f0.y*f0.y + f1.x*f1.x + f1.y*f1.y \
                 + f2.x*f2.x + f2.y*f2.y + f3.x*f3.x + f3.y*f3.y; \
        sp += __shfl_xor(sp, 1); \
        sc##i = sp / ((0.5f + sp) * (sqrtf(sp + 1e-6f) + 1e-6f)); }
    FOR8(SC)
#undef SC

#define BRI(i) float br##i = 0.f;
    FOR8(BRI)
#undef BRI

    float s0, s1, s2, s3, s4, s5, s6, s7;
#pragma unroll
    for (int it = 0; it < 2; ++it) {
#define CSC(i) float cs##i = sc##i / (1.f + __expf(-br##i));
        FOR8(CSC)
#undef CSC
        s0 = s1 = s2 = s3 = s4 = s5 = s6 = s7 = 0.f;
#define SVA(i) { UNP(i) \
        s0 = fmaf(f0.x, cs##i, s0); s1 = fmaf(f0.y, cs##i, s1); \
        s2 = fmaf(f1.x, cs##i, s2); s3 = fmaf(f1.y, cs##i, s3); \
        s4 = fmaf(f2.x, cs##i, s4); s5 = fmaf(f2.y, cs##i, s5); \
        s6 = fmaf(f3.x, cs##i, s6); s7 = fmaf(f3.y, cs##i, s7); }
        FOR8(SVA)
#undef SVA
        float sp = s0*s0 + s1*s1 + s2*s2 + s3*s3 + s4*s4 + s5*s5 + s6*s6 + s7*s7;
        sp += __shfl_xor(sp, 1);
        float f = sp / ((0.5f + sp) * (sqrtf(sp + 1e-6f) + 1e-6f));
#define DOTD(i) { UNP(i) \
        float dp = f0.x*s0 + f0.y*s1 + f1.x*s2 + f1.y*s3 + f2.x*s4 + f2.y*s5 + f3.x*s6 + f3.y*s7; \
        dp += __shfl_xor(dp, 1); \
        br##i = fmaf(sc##i * f, dp, br##i); }
        FOR8(DOTD)
#undef DOTD
    }

#define CF(i) float cf##i = 1.f / (1.f + __expf(-br##i));
    FOR8(CF)
#undef CF
    s0 = s1 = s2 = s3 = s4 = s5 = s6 = s7 = 0.f;
#define FS(i) { UNP(i) \
        s0 = fmaf(f0.x, cf##i, s0); s1 = fmaf(f0.y, cf##i, s1); \
        s2 = fmaf(f1.x, cf##i, s2); s3 = fmaf(f1.y, cf##i, s3); \
        s4 = fmaf(f2.x, cf##i, s4); s5 = fmaf(f2.y, cf##i, s5); \
        s6 = fmaf(f3.x, cf##i, s6); s7 = fmaf(f3.y, cf##i, s7); }
    FOR8(FS)
#undef FS
#undef UNP

    {
        uint4 pk;
        pk.x = h2u(__floats2half2_rn(s0, s1));
        pk.y = h2u(__floats2half2_rn(s2, s3));
        pk.z = h2u(__floats2half2_rn(s4, s5));
        pk.w = h2u(__floats2half2_rn(s6, s7));
        *(uint4*)&us[px * 1024 + ((oc * 16 + odh * 8) ^ ssw)] = pk;
    }

    {
        float p0 = s0, p1 = s1, p2 = s2, p3 = s3, p4 = s4, p5 = s5, p6 = s6, p7 = s7;
#pragma unroll
        for (int m = 16; m <= 32; m <<= 1) {
            p0 += __shfl_xor(p0, m); p1 += __shfl_xor(p1, m);
            p2 += __shfl_xor(p2, m); p3 += __shfl_xor(p3, m);
            p4 += __shfl_xor(p4, m); p5 += __shfl_xor(p5, m);
            p6 += __shfl_xor(p6, m); p7 += __shfl_xor(p7, m);
        }
        if ((l & 48) == 0) {
            float* wr = wred[w][oc * 2 + odh];
            wr[0] = p0; wr[1] = p1; wr[2] = p2; wr[3] = p3;
            wr[4] = p4; wr[5] = p5; wr[6] = p6; wr[7] = p7;
        }
    }
    __syncthreads();

    {
        int oc2 = w;
        int pxw = l >> 1, half = l & 1;
        int ch2 = (oc2 * 16 + half * 8) ^ ((pxw & 15) << 3);
        uint4 v = *(const uint4*)&us[pxw * 1024 + ch2];
        ushort* sb = sOut + ((size_t)(b * 8 + oc2) * 4096 + px0 + pxw) * 16 + half * 8;
        *(uint4*)sb = v;
    }
    if (t < 128) {
        int comb = t >> 3, j = t & 7;
        float a = 0.f;
#pragma unroll
        for (int ww = 0; ww < 8; ++ww) a += wred[ww][comb][j];
        int oc3 = comb >> 1, odh3 = comb & 1;
        part[((size_t)(b * 8 + oc3) * 128 + (bid & 127)) * 16 + odh3 * 8 + j] = a;
    }
}

// ---------------- K4: reduce partials -> mean_hw; avg + stats ----------------
__global__ __launch_bounds__(256) void k4_avg(const ushort* __restrict__ sIn, const float* __restrict__ part,
                                              float* __restrict__ avg, float* __restrict__ stats) {
    __shared__ float mh[16];
    int bi = blockIdx.x;                 // bo*16 + chunk
    int chunk = bi & 15;
    int bo = bi >> 4;
    int t = threadIdx.x;
    int pos = chunk * 256 + t;

    if (t < 16) {
        float a = 0.f;
        for (int c = 0; c < 128; ++c) a += part[(size_t)(bo * 128 + c) * 16 + t];
        mh[t] = a * (1.f / 4096.f);
    }
    __syncthreads();

    const ushort* sb = sIn + ((size_t)bo * 4096 + pos) * 16;
    uint4 qa = *(const uint4*)&sb[0];
    uint4 qb = *(const uint4*)&sb[8];
    float2 f0 = __half22float2(u2h(qa.x)), f1 = __half22float2(u2h(qa.y));
    float2 f2 = __half22float2(u2h(qa.z)), f3 = __half22float2(u2h(qa.w));
    float2 f4 = __half22float2(u2h(qb.x)), f5 = __half22float2(u2h(qb.y));
    float2 f6 = __half22float2(u2h(qb.z)), f7 = __half22float2(u2h(qb.w));
    float a = f0.x * mh[0] + f0.y * mh[1] + f1.x * mh[2] + f1.y * mh[3]
            + f2.x * mh[4] + f2.y * mh[5] + f3.x * mh[6] + f3.y * mh[7]
            + f4.x * mh[8] + f4.y * mh[9] + f5.x * mh[10] + f5.y * mh[11]
            + f6.x * mh[12] + f6.y * mh[13] + f7.x * mh[14] + f7.y * mh[15];
    avg[(size_t)bo * 4096 + pos] = a;

    float p1 = a, p2 = a * a;
#pragma unroll
    for (int m = 1; m < 64; m <<= 1) {
        p1 += __shfl_xor(p1, m);
        p2 += __shfl_xor(p2, m);
    }
    if ((t & 63) == 0) {
        atomicAdd(&stats[bo * 2],     p1);
        atomicAdd(&stats[bo * 2 + 1], p2);
    }
}

// ---------------- K5: normalize, attn gate, residual ----------------
__global__ __launch_bounds__(256) void k5_out(const ushort* __restrict__ sIn, const float* __restrict__ x,
                                              const float* __restrict__ avg, const float* __restrict__ stats,
                                              const float* __restrict__ aw, const float* __restrict__ ab,
                                              float* __restrict__ out) {
    int bi = blockIdx.x;                 // bo*16 + chunk
    int chunk = bi & 15;
    int bo = bi >> 4;
    int oc = bo & 7;
    int pos = chunk * 256 + threadIdx.x;

    float sum = stats[bo * 2], sumsq = stats[bo * 2 + 1];
    float m   = sum * (1.f / 4096.f);
    float var = (sumsq - 4096.f * m * m) * (1.f / 4095.f);
    float sd  = sqrtf(fmaxf(var, 0.f)) + 1e-6f;

    float t   = (avg[(size_t)bo * 4096 + pos] - m) / sd * aw[oc] + ab[oc];
    float sig = 1.f / (1.f + __expf(-t));

    const ushort* sb = sIn + ((size_t)bo * 4096 + pos) * 16;
    uint4 qa = *(const uint4*)&sb[0];
    uint4 qb = *(const uint4*)&sb[8];
    float2 f0 = __half22float2(u2h(qa.x)), f1 = __half22float2(u2h(qa.y));
    float2 f2 = __half22float2(u2h(qa.z)), f3 = __half22float2(u2h(qa.w));
    float2 f4 = __half22float2(u2h(qb.x)), f5 = __half22float2(u2h(qb.y));
    float2 f6 = __half22float2(u2h(qb.z)), f7 = __half22float2(u2h(qb.w));
    float sv[16] = {f0.x, f0.y, f1.x, f1.y, f2.x, f2.y, f3.x, f3.y,
                    f4.x, f4.y, f5.x, f5.y, f6.x, f6.y, f7.x, f7.y};

    const float* xb = x + (size_t)bo * 16 * HW + pos;
    float* ob = out + (size_t)bo * 16 * HW + pos;
#pragma unroll
    for (int od = 0; od < 16; ++od) ob[od * HW] = fmaf(sv[od], sig, xb[od * HW]);
}

extern "C" void kernel_launch(void* const* d_in, const int* in_sizes, int n_in,
                              void* d_out, int out_size, void* d_ws, size_t ws_size,
                              hipStream_t stream) {
    const float* x  = (const float*)d_in[0];
    const float* w1 = (const float*)d_in[1];
    const float* b1 = (const float*)d_in[2];
    const float* w2 = (const float*)d_in[3];
    const float* b2 = (const float*)d_in[4];
    const float* w3 = (const float*)d_in[5];
    const float* b3 = (const float*)d_in[6];
    const float* aw = (const float*)d_in[7];
    const float* ab = (const float*)d_in[8];

    float* ws      = (float*)d_ws;
    ushort* h2g    = (ushort*)ws;                    // 8.4M halfs (16MB)
    ushort* sbuf   = (ushort*)(ws + 4194304);        // 4.2M halfs (8.4MB)
    float* avg     = ws + 4194304 + 2097152;         // 262,144 floats
    float* part    = avg + 262144;                   // 131,072 floats
    float* stats   = part + 131072;                  // 128
    ushort* w3h    = (ushort*)(stats + 128);         // 32,768 halfs
    ushort* w2f    = w3h + 32768;                    // 73,728 halfs

    k0_prep  <<<416, 256, 0, stream>>>(w3, w3h, w2, w2f, stats);
    k12_conv <<<1024, 256, 0, stream>>>(x, w1, b1, w2f, b2, h2g);
    k3f_route<<<1024, 512, 0, stream>>>(h2g, w3h, b3, sbuf, part);
    k4_avg   <<<1024, 256, 0, stream>>>(sbuf, part, avg, stats);
    k5_out   <<<1024, 256, 0, stream>>>(sbuf, x, avg, stats, aw, ab, (float*)d_out);
}

// Round 15
// 84.763 us; speedup vs baseline: 2.0182x; 1.0103x over previous
//
#include <hip/hip_runtime.h>
#include <hip/hip_bf16.h>
#include <hip/hip_fp16.h>

#define HW 4096

typedef _Float16 f16x8 __attribute__((ext_vector_type(8)));
typedef float f32x4 __attribute__((ext_vector_type(4)));

#define FOR8(X) X(0) X(1) X(2) X(3) X(4) X(5) X(6) X(7)

static __device__ __forceinline__ __half2 u2h(unsigned int u) {
    union { unsigned int u; __half2 h; } c; c.u = u; return c.h;
}
static __device__ __forceinline__ unsigned int h2u(__half2 h) {
    union { unsigned int u; __half2 h; } c; c.h = h; return c.u;
}

// ---------------- K0: weight prep (w3 A-frags + w2 A-frags + stats zero) ----------------
__global__ __launch_bounds__(256) void k0_prep(const float* __restrict__ w3, ushort* __restrict__ w3h,
                                               const float* __restrict__ w2, ushort* __restrict__ w2f,
                                               float* __restrict__ stats) {
    int bid = blockIdx.x;
    int t = threadIdx.x;
    if (bid == 0 && t < 128) stats[t] = 0.f;
    if (bid < 128) {
        int gi = bid * 256 + t;                    // 32768: w3h[p][lane][j]
        int j = gi & 7;
        int l = (gi >> 3) & 63;
        int p = gi >> 9;                           // ic*8+oc
        int ic = p >> 3, oc = p & 7;
        int od = l & 15;
        int m  = ((l >> 4) << 3) + j;
        w3h[gi] = __half_as_ushort(__float2half(w3[(size_t)((ic * 128 + oc * 16 + od) * 32 + m)]));
    } else {
        int gi = (bid - 128) * 256 + t;            // 73728: w2f[g][tap][h][lane][j]
        if (gi >= 73728) return;
        int j   = gi & 7;
        int l   = (gi >> 3) & 63;
        int h   = (gi >> 9) & 1;
        int tap = (gi >> 10) % 9;
        int g   = gi / 9216;
        int co = h * 16 + (l & 15);
        int ci = ((l >> 4) << 3) + j;
        w2f[gi] = __half_as_ushort(__float2half(w2[(size_t)((g * 32 + co) * 32 + ci) * 9 + tap]));
    }
}

// ---------------- K12: fused conv1(LDS) + 3x3 conv2 MFMA, 4-row tiles ----------------
__global__ __launch_bounds__(256) void k12_conv(const float* __restrict__ x, const float* __restrict__ w1,
                                                const float* __restrict__ b1, const ushort* __restrict__ w2f,
                                                const float* __restrict__ b2, ushort* __restrict__ h2g) {
    __shared__ ushort h1s[6][66][40];

    int bi = blockIdx.x;                 // b*128 + g*16 + q
    int q  = bi & 15;
    int g  = (bi >> 4) & 7;
    int b  = bi >> 7;
    int y0 = q * 4;
    int t  = threadIdx.x;

    for (int i = t; i < 396; i += 256) {
        int r  = i / 66;
        int xi = i - r * 66;
        int yy = y0 + r - 1;
        int xx = xi - 1;
        bool valid = (yy >= 0) && (yy < 64) && (xx >= 0) && (xx < 64);
        ushort hv[32];
        if (valid) {
            const float* xb = x + (size_t)(b * 128 + g * 16) * HW + yy * 64 + xx;
            float xv[16];
#pragma unroll
            for (int i2 = 0; i2 < 16; ++i2) xv[i2] = fmaxf(xb[i2 * HW], 0.f);
            const float* wg = w1 + g * 512;
            const float* bg = b1 + g * 32;
#pragma unroll
            for (int m = 0; m < 32; ++m) {
                float acc = bg[m];
#pragma unroll
                for (int i2 = 0; i2 < 16; ++i2) acc = fmaf(xv[i2], wg[m * 16 + i2], acc);
                hv[m] = __half_as_ushort(__float2half(fmaxf(acc, 0.f)));
            }
        } else {
#pragma unroll
            for (int m = 0; m < 32; ++m) hv[m] = 0;
        }
        ushort* dst = &h1s[r][xi][0];
#pragma unroll
        for (int q2 = 0; q2 < 4; ++q2) *(uint4*)&dst[q2 * 8] = *(uint4*)&hv[q2 * 8];
    }
    __syncthreads();

    int w  = t >> 6, l = t & 63;
    int lrow = l & 15, kgrp = l >> 4;
    int yloc = w;
    const ushort* wg2 = w2f + (size_t)g * 9216;

    float4 bias0 = *(const float4*)(b2 + g * 32 + kgrp * 4);
    float4 bias1 = *(const float4*)(b2 + g * 32 + 16 + kgrp * 4);

#pragma unroll
    for (int tile = 0; tile < 4; ++tile) {
        int xcol = tile * 16 + lrow;
        f32x4 acc0, acc1;
        acc0[0] = bias0.x; acc0[1] = bias0.y; acc0[2] = bias0.z; acc0[3] = bias0.w;
        acc1[0] = bias1.x; acc1[1] = bias1.y; acc1[2] = bias1.z; acc1[3] = bias1.w;
#pragma unroll
        for (int tap = 0; tap < 9; ++tap) {
            int dy = tap / 3, dx = tap - dy * 3;
            f16x8 Bf = *(const f16x8*)&h1s[yloc + dy][xcol + dx][kgrp * 8];
            f16x8 A0 = *(const f16x8*)&wg2[((tap * 2 + 0) * 64 + l) * 8];
            f16x8 A1 = *(const f16x8*)&wg2[((tap * 2 + 1) * 64 + l) * 8];
            acc0 = __builtin_amdgcn_mfma_f32_16x16x32_f16(A0, Bf, acc0, 0, 0, 0);
            acc1 = __builtin_amdgcn_mfma_f32_16x16x32_f16(A1, Bf, acc1, 0, 0, 0);
        }
        int px = (y0 + yloc) * 64 + xcol;
        ushort* ob = h2g + ((size_t)(b * 8 + g) * HW + px) * 32;
        uint2 wv0, wv1;
        wv0.x = h2u(__floats2half2_rn(fmaxf(acc0[0], 0.f), fmaxf(acc0[1], 0.f)));
        wv0.y = h2u(__floats2half2_rn(fmaxf(acc0[2], 0.f), fmaxf(acc0[3], 0.f)));
        wv1.x = h2u(__floats2half2_rn(fmaxf(acc1[0], 0.f), fmaxf(acc1[1], 0.f)));
        wv1.y = h2u(__floats2half2_rn(fmaxf(acc1[2], 0.f), fmaxf(acc1[3], 0.f)));
        *(uint2*)&ob[kgrp * 4] = wv0;
        *(uint2*)&ob[16 + kgrp * 4] = wv1;
    }
}

// ---------------- K3f: fused conv3 MFMA + routing; packed-fp16 routing math ----------------
__global__ __launch_bounds__(512) void k3f_route(const ushort* __restrict__ h2g, const ushort* __restrict__ w3h,
                                                 const float* __restrict__ b3, ushort* __restrict__ sOut,
                                                 float* __restrict__ part) {
    __shared__ ushort us[32 * 1024];
    __shared__ float wred[8][16][8];
    int bid = blockIdx.x;               // b*128 + tile
    int b   = bid >> 7;
    int px0 = (bid & 127) << 5;
    int t   = threadIdx.x;
    int w   = t >> 6, l = t & 63;

    // ---- phase A: conv3 MFMA, wave = ic ----
    {
        int ic = w;
        int lrow = l & 15, lk = l >> 4;
        f16x8 bf0 = *(const f16x8*)&h2g[(((size_t)(b * 8 + ic)) * HW + px0 + lrow) * 32 + lk * 8];
        f16x8 bf1 = *(const f16x8*)&h2g[(((size_t)(b * 8 + ic)) * HW + px0 + 16 + lrow) * 32 + lk * 8];
        int s0sw = (lrow & 15) << 3;
#pragma unroll
        for (int oc = 0; oc < 8; ++oc) {
            f16x8 af = *(const f16x8*)&w3h[((ic * 8 + oc) * 64 + l) * 8];
            float4 bv = *(const float4*)(b3 + ic * 128 + oc * 16 + lk * 4);
            f32x4 c0; c0[0] = bv.x; c0[1] = bv.y; c0[2] = bv.z; c0[3] = bv.w;
            int ch = ic * 128 + oc * 16 + lk * 4;
            f32x4 d0 = __builtin_amdgcn_mfma_f32_16x16x32_f16(af, bf0, c0, 0, 0, 0);
            uint2 wv0;
            wv0.x = h2u(__floats2half2_rn(d0[0], d0[1]));
            wv0.y = h2u(__floats2half2_rn(d0[2], d0[3]));
            *(uint2*)&us[lrow * 1024 + (ch ^ s0sw)] = wv0;
            f32x4 d1 = __builtin_amdgcn_mfma_f32_16x16x32_f16(af, bf1, c0, 0, 0, 0);
            uint2 wv1;
            wv1.x = h2u(__floats2half2_rn(d1[0], d1[1]));
            wv1.y = h2u(__floats2half2_rn(d1[2], d1[3]));
            *(uint2*)&us[(16 + lrow) * 1024 + (ch ^ s0sw)] = wv1;
        }
    }
    __syncthreads();

    // ---- phase B: routing (packed fp16 summations, f32 norms/sigmoid) ----
    int px  = t >> 4;
    int oc  = (t >> 1) & 7;
    int odh = t & 1;
    int ssw = (px & 15) << 3;
    const ushort* ur = &us[px * 1024];
#define LDQ(i) uint4 q##i = *(const uint4*)&ur[((i) * 128 + oc * 16 + odh * 8) ^ ssw];
    FOR8(LDQ)
#undef LDQ
    __syncthreads();

    // squash scale per ic: ||u||^2 via pk_fma, f32 finish
#define SC(i) float sc##i; { \
        __half2 a0 = u2h(q##i.x), a1 = u2h(q##i.y), a2 = u2h(q##i.z), a3 = u2h(q##i.w); \
        __half2 s2 = __hmul2(a0, a0); s2 = __hfma2(a1, a1, s2); \
        s2 = __hfma2(a2, a2, s2); s2 = __hfma2(a3, a3, s2); \
        float2 fq = __half22float2(s2); \
        float sp = fq.x + fq.y; \
        sp += __shfl_xor(sp, 1); \
        sc##i = sp / ((0.5f + sp) * (sqrtf(sp + 1e-6f) + 1e-6f)); }
    FOR8(SC)
#undef SC

#define BRI(i) float br##i = 0.f;
    FOR8(BRI)
#undef BRI

    __half2 sh0, sh1, sh2, sh3;
#pragma unroll
    for (int it = 0; it < 2; ++it) {
#define CSC(i) __half2 cs##i = __float2half2_rn(sc##i / (1.f + __expf(-br##i)));
        FOR8(CSC)
#undef CSC
        sh0 = sh1 = sh2 = sh3 = __float2half2_rn(0.f);
#define SVA(i) { sh0 = __hfma2(u2h(q##i.x), cs##i, sh0); sh1 = __hfma2(u2h(q##i.y), cs##i, sh1); \
                 sh2 = __hfma2(u2h(q##i.z), cs##i, sh2); sh3 = __hfma2(u2h(q##i.w), cs##i, sh3); }
        FOR8(SVA)
#undef SVA
        __half2 n2 = __hmul2(sh0, sh0); n2 = __hfma2(sh1, sh1, n2);
        n2 = __hfma2(sh2, sh2, n2); n2 = __hfma2(sh3, sh3, n2);
        float2 nf = __half22float2(n2);
        float sp = nf.x + nf.y;
        sp += __shfl_xor(sp, 1);
        float fsq = sp / ((0.5f + sp) * (sqrtf(sp + 1e-6f) + 1e-6f));
#define DOTD(i) { __half2 d2 = __hmul2(u2h(q##i.x), sh0); d2 = __hfma2(u2h(q##i.y), sh1, d2); \
        d2 = __hfma2(u2h(q##i.z), sh2, d2); d2 = __hfma2(u2h(q##i.w), sh3, d2); \
        float2 df = __half22float2(d2); float dp = df.x + df.y; \
        dp += __shfl_xor(dp, 1); \
        br##i = fmaf(sc##i * fsq, dp, br##i); }
        FOR8(DOTD)
#undef DOTD
    }

#define CF(i) __half2 cf##i = __float2half2_rn(1.f / (1.f + __expf(-br##i)));
    FOR8(CF)
#undef CF
    sh0 = sh1 = sh2 = sh3 = __float2half2_rn(0.f);
#define FS(i) { sh0 = __hfma2(u2h(q##i.x), cf##i, sh0); sh1 = __hfma2(u2h(q##i.y), cf##i, sh1); \
                sh2 = __hfma2(u2h(q##i.z), cf##i, sh2); sh3 = __hfma2(u2h(q##i.w), cf##i, sh3); }
    FOR8(FS)
#undef FS

    // stage s (already packed) into dead u region
    {
        uint4 pk;
        pk.x = h2u(sh0); pk.y = h2u(sh1); pk.z = h2u(sh2); pk.w = h2u(sh3);
        *(uint4*)&us[px * 1024 + ((oc * 16 + odh * 8) ^ ssw)] = pk;
    }

    // per-wave mean partial (f32 unpack once)
    {
        float2 g0 = __half22float2(sh0), g1 = __half22float2(sh1);
        float2 g2 = __half22float2(sh2), g3 = __half22float2(sh3);
        float p0 = g0.x, p1 = g0.y, p2 = g1.x, p3 = g1.y;
        float p4 = g2.x, p5 = g2.y, p6 = g3.x, p7 = g3.y;
#pragma unroll
        for (int m = 16; m <= 32; m <<= 1) {
            p0 += __shfl_xor(p0, m); p1 += __shfl_xor(p1, m);
            p2 += __shfl_xor(p2, m); p3 += __shfl_xor(p3, m);
            p4 += __shfl_xor(p4, m); p5 += __shfl_xor(p5, m);
            p6 += __shfl_xor(p6, m); p7 += __shfl_xor(p7, m);
        }
        if ((l & 48) == 0) {
            float* wr = wred[w][oc * 2 + odh];
            wr[0] = p0; wr[1] = p1; wr[2] = p2; wr[3] = p3;
            wr[4] = p4; wr[5] = p5; wr[6] = p6; wr[7] = p7;
        }
    }
    __syncthreads();

    {
        int oc2 = w;
        int pxw = l >> 1, half = l & 1;
        int ch2 = (oc2 * 16 + half * 8) ^ ((pxw & 15) << 3);
        uint4 v = *(const uint4*)&us[pxw * 1024 + ch2];
        ushort* sb = sOut + ((size_t)(b * 8 + oc2) * 4096 + px0 + pxw) * 16 + half * 8;
        *(uint4*)sb = v;
    }
    if (t < 128) {
        int comb = t >> 3, j = t & 7;
        float a = 0.f;
#pragma unroll
        for (int ww = 0; ww < 8; ++ww) a += wred[ww][comb][j];
        int oc3 = comb >> 1, odh3 = comb & 1;
        part[((size_t)(b * 8 + oc3) * 128 + (bid & 127)) * 16 + odh3 * 8 + j] = a;
    }
}

// ---------------- K4: reduce partials -> mh; stats (no avg buffer) ----------------
__global__ __launch_bounds__(256) void k4_stats(const ushort* __restrict__ sIn, const float* __restrict__ part,
                                                float* __restrict__ mhOut, float* __restrict__ stats) {
    __shared__ float mh[16];
    int bi = blockIdx.x;                 // bo*16 + chunk
    int chunk = bi & 15;
    int bo = bi >> 4;
    int t = threadIdx.x;
    int pos = chunk * 256 + t;

    if (t < 16) {
        float a = 0.f;
        for (int c = 0; c < 128; ++c) a += part[(size_t)(bo * 128 + c) * 16 + t];
        float v = a * (1.f / 4096.f);
        mh[t] = v;
        if (chunk == 0) mhOut[bo * 16 + t] = v;
    }
    __syncthreads();

    const ushort* sb = sIn + ((size_t)bo * 4096 + pos) * 16;
    uint4 qa = *(const uint4*)&sb[0];
    uint4 qb = *(const uint4*)&sb[8];
    float2 f0 = __half22float2(u2h(qa.x)), f1 = __half22float2(u2h(qa.y));
    float2 f2 = __half22float2(u2h(qa.z)), f3 = __half22float2(u2h(qa.w));
    float2 f4 = __half22float2(u2h(qb.x)), f5 = __half22float2(u2h(qb.y));
    float2 f6 = __half22float2(u2h(qb.z)), f7 = __half22float2(u2h(qb.w));
    float a = f0.x * mh[0] + f0.y * mh[1] + f1.x * mh[2] + f1.y * mh[3]
            + f2.x * mh[4] + f2.y * mh[5] + f3.x * mh[6] + f3.y * mh[7]
            + f4.x * mh[8] + f4.y * mh[9] + f5.x * mh[10] + f5.y * mh[11]
            + f6.x * mh[12] + f6.y * mh[13] + f7.x * mh[14] + f7.y * mh[15];

    float p1 = a, p2 = a * a;
#pragma unroll
    for (int m = 1; m < 64; m <<= 1) {
        p1 += __shfl_xor(p1, m);
        p2 += __shfl_xor(p2, m);
    }
    if ((t & 63) == 0) {
        atomicAdd(&stats[bo * 2],     p1);
        atomicAdd(&stats[bo * 2 + 1], p2);
    }
}

// ---------------- K5: recompute avg from sbuf+mh, normalize, gate, residual ----------------
__global__ __launch_bounds__(256) void k5_out(const ushort* __restrict__ sIn, const float* __restrict__ x,
                                              const float* __restrict__ mhIn, const float* __restrict__ stats,
                                              const float* __restrict__ aw, const float* __restrict__ ab,
                                              float* __restrict__ out) {
    __shared__ float mh[16];
    int bi = blockIdx.x;                 // bo*16 + chunk
    int chunk = bi & 15;
    int bo = bi >> 4;
    int oc = bo & 7;
    int t = threadIdx.x;
    int pos = chunk * 256 + t;

    if (t < 16) mh[t] = mhIn[bo * 16 + t];
    __syncthreads();

    float sum = stats[bo * 2], sumsq = stats[bo * 2 + 1];
    float m   = sum * (1.f / 4096.f);
    float var = (sumsq - 4096.f * m * m) * (1.f / 4095.f);
    float sd  = sqrtf(fmaxf(var, 0.f)) + 1e-6f;

    const ushort* sb = sIn + ((size_t)bo * 4096 + pos) * 16;
    uint4 qa = *(const uint4*)&sb[0];
    uint4 qb = *(const uint4*)&sb[8];
    float2 f0 = __half22float2(u2h(qa.x)), f1 = __half22float2(u2h(qa.y));
    float2 f2 = __half22float2(u2h(qa.z)), f3 = __half22float2(u2h(qa.w));
    float2 f4 = __half22float2(u2h(qb.x)), f5 = __half22float2(u2h(qb.y));
    float2 f6 = __half22float2(u2h(qb.z)), f7 = __half22float2(u2h(qb.w));
    float sv[16] = {f0.x, f0.y, f1.x, f1.y, f2.x, f2.y, f3.x, f3.y,
                    f4.x, f4.y, f5.x, f5.y, f6.x, f6.y, f7.x, f7.y};

    float a = 0.f;
#pragma unroll
    for (int od = 0; od < 16; ++od) a = fmaf(sv[od], mh[od], a);

    float tt  = (a - m) / sd * aw[oc] + ab[oc];
    float sig = 1.f / (1.f + __expf(-tt));

    const float* xb = x + (size_t)bo * 16 * HW + pos;
    float* ob = out + (size_t)bo * 16 * HW + pos;
#pragma unroll
    for (int od = 0; od < 16; ++od) ob[od * HW] = fmaf(sv[od], sig, xb[od * HW]);
}

extern "C" void kernel_launch(void* const* d_in, const int* in_sizes, int n_in,
                              void* d_out, int out_size, void* d_ws, size_t ws_size,
                              hipStream_t stream) {
    const float* x  = (const float*)d_in[0];
    const float* w1 = (const float*)d_in[1];
    const float* b1 = (const float*)d_in[2];
    const float* w2 = (const float*)d_in[3];
    const float* b2 = (const float*)d_in[4];
    const float* w3 = (const float*)d_in[5];
    const float* b3 = (const float*)d_in[6];
    const float* aw = (const float*)d_in[7];
    const float* ab = (const float*)d_in[8];

    float* ws      = (float*)d_ws;
    ushort* h2g    = (ushort*)ws;                    // 8.4M halfs (16MB)
    ushort* sbuf   = (ushort*)(ws + 4194304);        // 4.2M halfs (8.4MB)
    float* part    = ws + 4194304 + 2097152;         // 131,072 floats
    float* stats   = part + 131072;                  // 128
    float* mhBuf   = stats + 128;                    // 1024
    ushort* w3h    = (ushort*)(mhBuf + 1024);        // 32,768 halfs
    ushort* w2f    = w3h + 32768;                    // 73,728 halfs

    k0_prep  <<<416, 256, 0, stream>>>(w3, w3h, w2, w2f, stats);
    k12_conv <<<1024, 256, 0, stream>>>(x, w1, b1, w2f, b2, h2g);
    k3f_route<<<1024, 512, 0, stream>>>(h2g, w3h, b3, sbuf, part);
    k4_stats <<<1024, 256, 0, stream>>>(sbuf, part, mhBuf, stats);
    k5_out   <<<1024, 256, 0, stream>>>(sbuf, x, mhBuf, stats, aw, ab, (float*)d_out);
}